// Round 1
// baseline (2566.495 us; speedup 1.0000x reference)
//
#include <hip/hip_runtime.h>

// CurvGN 2-layer graph net, N=100k nodes, E=3.2M edges, 256->64->16.
// Key algebra: edge-MLP logits = w_mul[e] * (w>0 ? gpos[i] : gneg[i]) + b2[i];
// b2 cancels in per-src segment softmax. Segment max from 4 per-src endpoints.
// out[d][i] = sum_e exp(w_e*g_i) * q[src][i],  q = x*exp(-m)/(den+1e-16).

static __device__ __forceinline__ unsigned fkey(float f) {
  unsigned u = __float_as_uint(f);
  return (u & 0x80000000u) ? ~u : (u | 0x80000000u);   // monotone float->uint
}
static __device__ __forceinline__ float unfkey(unsigned k) {
  unsigned u = (k & 0x80000000u) ? (k ^ 0x80000000u) : ~k;
  return __uint_as_float(u);
}
static __device__ __forceinline__ int ld_idx(const void* ei, long long pos, int is64) {
  return is64 ? (int)((const long long*)ei)[pos] : ((const int*)ei)[pos];
}
// max over segment logits (no b2) from per-sign endpoints
static __device__ __forceinline__ float seg_max_m(unsigned pmax, unsigned pmin,
                                                  unsigned nmax, unsigned nmin,
                                                  int zf, float gp, float gn) {
  float m = -3.0e38f;
  if (pmax) { float a = unfkey(pmax), b = unfkey(pmin); m = fmaxf(m, gp > 0.f ? a * gp : b * gp); }
  if (nmax) { float a = unfkey(nmax), b = unfkey(nmin); m = fmaxf(m, gn > 0.f ? a * gn : b * gn); }
  if (zf)   m = fmaxf(m, 0.f);
  return m;
}

// ---- K1: collapse edge MLPs: g[0:64]=gpos1 g[64:128]=gneg1 g[128:144]=gpos2 g[144:160]=gneg2
__global__ void gvec_k(const float* __restrict__ w1a, const float* __restrict__ w2a,
                       const float* __restrict__ w1b, const float* __restrict__ w2b,
                       float* __restrict__ g) {
  int i = threadIdx.x;
  if (i < 64) {
    float sp = 0.f, sn = 0.f;
    for (int j = 0; j < 64; ++j) {
      float a = w1a[j], b = w2a[i * 64 + j], ab = a * b;
      sp += ab * (a > 0.f ? 1.f : 0.2f);
      sn += ab * (a < 0.f ? 1.f : 0.2f);
    }
    g[i] = sp; g[64 + i] = sn;
  }
  if (i < 16) {
    float sp = 0.f, sn = 0.f;
    for (int j = 0; j < 16; ++j) {
      float a = w1b[j], b = w2b[i * 16 + j], ab = a * b;
      sp += ab * (a > 0.f ? 1.f : 0.2f);
      sn += ab * (a < 0.f ? 1.f : 0.2f);
    }
    g[128 + i] = sp; g[144 + i] = sn;
  }
}

// ---- K2: degrees + per-src w endpoints
__global__ void edge_stats_k(const void* __restrict__ ei, const float* __restrict__ wm,
                             int* degS, int* degD,
                             unsigned* pmaxk, unsigned* pmink, unsigned* nmaxk, unsigned* nmink,
                             int* zflag, int E) {
  __shared__ int s64;
  if (threadIdx.x == 0) {
    const unsigned* u = (const unsigned*)ei;
    unsigned o = 0;
    int lim = (2 * E < 32) ? 2 * E : 32;
    for (int t = 1; t < lim; t += 2) o |= u[t];
    s64 = (o == 0u);   // int64 little-endian: high words of small nonneg values are 0
  }
  __syncthreads();
  int is64 = s64;
  long long stride = (long long)gridDim.x * blockDim.x;
  for (long long e = (long long)blockIdx.x * blockDim.x + threadIdx.x; e < E; e += stride) {
    int s = ld_idx(ei, e, is64);
    int d = ld_idx(ei, e + E, is64);
    float w = wm[e];
    atomicAdd(&degS[s], 1);
    atomicAdd(&degD[d], 1);
    if (w > 0.f)      { unsigned k = fkey(w); atomicMax(&pmaxk[s], k); atomicMin(&pmink[s], k); }
    else if (w < 0.f) { unsigned k = fkey(w); atomicMax(&nmaxk[s], k); atomicMin(&nmink[s], k); }
    else zflag[s] = 1;
  }
}

// ---- scan (3 kernels); handles both deg arrays (a = blockIdx / NB)
__global__ void scanA_k(const int* __restrict__ degS, const int* __restrict__ degD,
                        int* __restrict__ bsum, int N, int NB) {
  int b = blockIdx.x, a = b / NB, bb = b % NB;
  const int* deg = a ? degD : degS;
  int i = bb * 1024 + threadIdx.x;
  int v = (i < N) ? deg[i] : 0;
  int lane = threadIdx.x & 63, wid = threadIdx.x >> 6;
  #pragma unroll
  for (int d = 32; d > 0; d >>= 1) v += __shfl_xor(v, d);
  __shared__ int ws_[16];
  if (lane == 0) ws_[wid] = v;
  __syncthreads();
  if (threadIdx.x == 0) {
    int s = 0;
    for (int t = 0; t < 16; ++t) s += ws_[t];
    bsum[a * 256 + bb] = s;
  }
}
__global__ void scanB_k(const int* __restrict__ bsum, int* __restrict__ bsumx,
                        int* offS, int* offD, int N, int NB) {
  for (int a = 0; a < 2; ++a) {
    int c = 0;
    for (int b = 0; b < NB; ++b) { bsumx[a * 256 + b] = c; c += bsum[a * 256 + b]; }
    (a ? offD : offS)[N] = c;
  }
}
__global__ void scanC_k(const int* __restrict__ degS, const int* __restrict__ degD,
                        const int* __restrict__ bsumx,
                        int* offS, int* offD, int* curS, int* curD, int N, int NB) {
  int b = blockIdx.x, a = b / NB, bb = b % NB;
  const int* deg = a ? degD : degS;
  int* off = a ? offD : offS;
  int* cur = a ? curD : curS;
  int i = bb * 1024 + threadIdx.x;
  int v = (i < N) ? deg[i] : 0;
  int lane = threadIdx.x & 63, wid = threadIdx.x >> 6;
  int x = v;
  #pragma unroll
  for (int d = 1; d < 64; d <<= 1) { int t = __shfl_up(x, d); if (lane >= d) x += t; }
  __shared__ int ws_[16];
  if (lane == 63) ws_[wid] = x;
  __syncthreads();
  if (wid == 0) {
    int s = (lane < 16) ? ws_[lane] : 0;
    #pragma unroll
    for (int d = 1; d < 16; d <<= 1) { int t = __shfl_up(s, d); if (lane >= d) s += t; }
    if (lane < 16) ws_[lane] = s;
  }
  __syncthreads();
  int add = (wid ? ws_[wid - 1] : 0) + bsumx[a * 256 + bb];
  if (i < N) { int ex = add + x - v; off[i] = ex; cur[i] = ex; }
}

// ---- K4: scatter into CSR (order within a segment is irrelevant)
__global__ void scatter_k(const void* __restrict__ ei, const float* __restrict__ wm,
                          int* curS, int* curD,
                          float* __restrict__ csw, int* __restrict__ csds, float* __restrict__ csdw,
                          int E) {
  __shared__ int s64;
  if (threadIdx.x == 0) {
    const unsigned* u = (const unsigned*)ei;
    unsigned o = 0;
    int lim = (2 * E < 32) ? 2 * E : 32;
    for (int t = 1; t < lim; t += 2) o |= u[t];
    s64 = (o == 0u);
  }
  __syncthreads();
  int is64 = s64;
  long long stride = (long long)gridDim.x * blockDim.x;
  for (long long e = (long long)blockIdx.x * blockDim.x + threadIdx.x; e < E; e += stride) {
    int s = ld_idx(ei, e, is64);
    int d = ld_idx(ei, e + E, is64);
    float w = wm[e];
    int ps = atomicAdd(&curS[s], 1);
    csw[ps] = w;
    int pd = atomicAdd(&curD[d], 1);
    csds[pd] = s;
    csdw[pd] = w;
  }
}

// ---- K5: x1 = x @ lin1_w.T + b   (N x 256) x (64 x 256)^T -> N x 64
__global__ __launch_bounds__(256) void gemm1_k(const float* __restrict__ x,
                                               const float* __restrict__ W,
                                               const float* __restrict__ b,
                                               float* __restrict__ x1, int N) {
  __shared__ __align__(16) float Wl[64 * 260];   // pad 256->260 to break bank stride
  for (int c = threadIdx.x; c < 64 * 64; c += 256) {
    int r = c >> 6, q4 = c & 63;
    *(float4*)&Wl[r * 260 + q4 * 4] = *(const float4*)&W[r * 256 + q4 * 4];
  }
  __syncthreads();
  int i = threadIdx.x & 63, gidx = threadIdx.x >> 6;
  int n0 = blockIdx.x * 32 + gidx * 8;
  float acc[8] = {0.f, 0.f, 0.f, 0.f, 0.f, 0.f, 0.f, 0.f};
  for (int k = 0; k < 256; k += 4) {
    float4 w4 = *(const float4*)&Wl[i * 260 + k];
    #pragma unroll
    for (int j = 0; j < 8; ++j) {
      int n = n0 + j;
      if (n < N) {
        float4 xv = *(const float4*)&x[(long long)n * 256 + k];
        acc[j] += xv.x * w4.x + xv.y * w4.y + xv.z * w4.z + xv.w * w4.w;
      }
    }
  }
  float bi = b[i];
  #pragma unroll
  for (int j = 0; j < 8; ++j) {
    int n = n0 + j;
    if (n < N) x1[(long long)n * 64 + i] = acc[j] + bi;
  }
}

// ---- K6: q1 = x1 * exp(-m)/(den+1e-16), one wave per src node, lane = channel
__global__ void node_q1_k(float* __restrict__ x1q1, const int* __restrict__ offS,
                          const float* __restrict__ csw,
                          const unsigned* __restrict__ pmaxk, const unsigned* __restrict__ pmink,
                          const unsigned* __restrict__ nmaxk, const unsigned* __restrict__ nmink,
                          const int* __restrict__ zflag, const float* __restrict__ g, int N) {
  int wv = (int)(((long long)blockIdx.x * blockDim.x + threadIdx.x) >> 6);
  if (wv >= N) return;
  int lane = threadIdx.x & 63;
  int s = wv;
  int beg = offS[s], end = offS[s + 1];
  long long o = (long long)s * 64 + lane;
  if (beg == end) { x1q1[o] = 0.f; return; }
  float gp = g[lane], gn = g[64 + lane];
  float m = seg_max_m(pmaxk[s], pmink[s], nmaxk[s], nmink[s], zflag[s], gp, gn);
  float den = 0.f;
  for (int t = beg; t < end; ++t) {
    float w = csw[t];
    den += __expf(w * (w > 0.f ? gp : gn) - m);
  }
  x1q1[o] = x1q1[o] * (__expf(-m) / (den + 1e-16f));
}

// ---- K7: h[d] = elu( sum_in exp(w*g)*q1[src] ), one wave per dst node
__global__ void msg1_k(const float* __restrict__ q1, float* __restrict__ h,
                       const int* __restrict__ offD, const int* __restrict__ csds,
                       const float* __restrict__ csdw, const float* __restrict__ g, int N) {
  int wv = (int)(((long long)blockIdx.x * blockDim.x + threadIdx.x) >> 6);
  if (wv >= N) return;
  int lane = threadIdx.x & 63;
  int d = wv;
  int beg = offD[d], end = offD[d + 1];
  float gp = g[lane], gn = g[64 + lane];
  float acc = 0.f;
  for (int t = beg; t < end; ++t) {
    int s = csds[t];
    float w = csdw[t];
    acc += __expf(w * (w > 0.f ? gp : gn)) * q1[(long long)s * 64 + lane];
  }
  h[(long long)d * 64 + lane] = acc > 0.f ? acc : (__expf(acc) - 1.f);
}

// ---- K5b: x2 = h @ lin2_w.T + b   (N x 64) x (16 x 64)^T -> N x 16
__global__ void gemm2_k(const float* __restrict__ h, const float* __restrict__ W,
                        const float* __restrict__ b, float* __restrict__ x2, int N) {
  long long idx = (long long)blockIdx.x * blockDim.x + threadIdx.x;
  if (idx >= (long long)N * 16) return;
  int n = (int)(idx >> 4), i = (int)(idx & 15);
  const float* hr = h + (long long)n * 64;
  const float* wr = W + i * 64;
  float acc = 0.f;
  #pragma unroll
  for (int k = 0; k < 64; k += 4) {
    float4 a = *(const float4*)&hr[k];
    float4 w4 = *(const float4*)&wr[k];
    acc += a.x * w4.x + a.y * w4.y + a.z * w4.z + a.w * w4.w;
  }
  x2[idx] = acc + b[i];
}

// ---- K8: q2 (16 channels, 4-way edge-parallel within the wave)
__global__ void node_q2_k(float* __restrict__ x2q2, const int* __restrict__ offS,
                          const float* __restrict__ csw,
                          const unsigned* __restrict__ pmaxk, const unsigned* __restrict__ pmink,
                          const unsigned* __restrict__ nmaxk, const unsigned* __restrict__ nmink,
                          const int* __restrict__ zflag, const float* __restrict__ g, int N) {
  int wv = (int)(((long long)blockIdx.x * blockDim.x + threadIdx.x) >> 6);
  if (wv >= N) return;
  int lane = threadIdx.x & 63, i = lane & 15, p = lane >> 4;
  int s = wv;
  int beg = offS[s], end = offS[s + 1];
  if (beg == end) { if (p == 0) x2q2[(long long)s * 16 + i] = 0.f; return; }
  float gp = g[128 + i], gn = g[144 + i];
  float m = seg_max_m(pmaxk[s], pmink[s], nmaxk[s], nmink[s], zflag[s], gp, gn);
  float den = 0.f;
  for (int t = beg + p; t < end; t += 4) {
    float w = csw[t];
    den += __expf(w * (w > 0.f ? gp : gn) - m);
  }
  den += __shfl_xor(den, 16);
  den += __shfl_xor(den, 32);
  if (p == 0) {
    long long o = (long long)s * 16 + i;
    x2q2[o] = x2q2[o] * (__expf(-m) / (den + 1e-16f));
  }
}

// ---- K9: out2 aggregation + log_softmax fused
__global__ void msg2_k(const float* __restrict__ q2, float* __restrict__ out,
                       const int* __restrict__ offD, const int* __restrict__ csds,
                       const float* __restrict__ csdw, const float* __restrict__ g, int N) {
  int wv = (int)(((long long)blockIdx.x * blockDim.x + threadIdx.x) >> 6);
  if (wv >= N) return;
  int lane = threadIdx.x & 63, i = lane & 15, p = lane >> 4;
  int d = wv;
  int beg = offD[d], end = offD[d + 1];
  float gp = g[128 + i], gn = g[144 + i];
  float accp = 0.f;
  for (int t = beg + p; t < end; t += 4) {
    int s = csds[t];
    float w = csdw[t];
    accp += __expf(w * (w > 0.f ? gp : gn)) * q2[(long long)s * 16 + i];
  }
  float acc = accp;
  acc += __shfl_xor(acc, 16);
  acc += __shfl_xor(acc, 32);
  // log_softmax across the 16 channels (lanes 0..15 within each p-group identical)
  float mx = acc;
  #pragma unroll
  for (int d2 = 1; d2 < 16; d2 <<= 1) mx = fmaxf(mx, __shfl_xor(mx, d2));
  float se = __expf(acc - mx);
  #pragma unroll
  for (int d2 = 1; d2 < 16; d2 <<= 1) se += __shfl_xor(se, d2);
  float ls = acc - mx - __logf(se);
  if (p == 0) out[(long long)d * 16 + i] = ls;
}

extern "C" void kernel_launch(void* const* d_in, const int* in_sizes, int n_in,
                              void* d_out, int out_size, void* d_ws, size_t ws_size,
                              hipStream_t stream) {
  const float* x    = (const float*)d_in[0];
  const void*  ei   = d_in[1];
  const float* wm   = (const float*)d_in[2];
  const float* l1w  = (const float*)d_in[3];
  const float* l1b  = (const float*)d_in[4];
  const float* m1w1 = (const float*)d_in[5];
  const float* m1w2 = (const float*)d_in[6];
  const float* l2w  = (const float*)d_in[8];
  const float* l2b  = (const float*)d_in[9];
  const float* m2w1 = (const float*)d_in[10];
  const float* m2w2 = (const float*)d_in[11];
  // mlp*_b2 (d_in[7], d_in[12]) cancel in the segment softmax — unused.

  int N = in_sizes[0] / 256;
  int E = in_sizes[2];
  float* out = (float*)d_out;

  char* base = (char*)d_ws;
  size_t off = 0;
  auto alloc = [&](size_t bytes) -> char* {
    char* p = base + off;
    off = (off + bytes + 255) & ~(size_t)255;
    return p;
  };
  char* zbeg = base + off;
  int* degS       = (int*)alloc((size_t)N * 4);
  int* degD       = (int*)alloc((size_t)N * 4);
  int* zflag      = (int*)alloc((size_t)N * 4);
  unsigned* pmaxk = (unsigned*)alloc((size_t)N * 4);
  unsigned* nmaxk = (unsigned*)alloc((size_t)N * 4);
  char* zend = base + off;
  char* fbeg = base + off;
  unsigned* pmink = (unsigned*)alloc((size_t)N * 4);
  unsigned* nmink = (unsigned*)alloc((size_t)N * 4);
  char* fend = base + off;
  int* offS  = (int*)alloc((size_t)(N + 1) * 4);
  int* offD  = (int*)alloc((size_t)(N + 1) * 4);
  int* curS  = (int*)alloc((size_t)N * 4);
  int* curD  = (int*)alloc((size_t)N * 4);
  float* g   = (float*)alloc(1024);
  int* bsum  = (int*)alloc(2 * 256 * 4);
  int* bsumx = (int*)alloc(2 * 256 * 4);
  float* csw  = (float*)alloc((size_t)E * 4);
  int*   csds = (int*)alloc((size_t)E * 4);
  float* csdw = (float*)alloc((size_t)E * 4);
  float* x1q1 = (float*)alloc((size_t)N * 64 * 4);   // x1, then q1 in-place
  float* h    = (float*)alloc((size_t)N * 64 * 4);
  float* x2q2 = (float*)alloc((size_t)N * 16 * 4);   // x2, then q2 in-place

  hipMemsetAsync(zbeg, 0, (size_t)(zend - zbeg), stream);
  hipMemsetAsync(fbeg, 0xFF, (size_t)(fend - fbeg), stream);

  gvec_k<<<1, 64, 0, stream>>>(m1w1, m1w2, m2w1, m2w2, g);
  edge_stats_k<<<2048, 256, 0, stream>>>(ei, wm, degS, degD, pmaxk, pmink, nmaxk, nmink, zflag, E);
  int NB = (N + 1023) / 1024;
  scanA_k<<<2 * NB, 1024, 0, stream>>>(degS, degD, bsum, N, NB);
  scanB_k<<<1, 1, 0, stream>>>(bsum, bsumx, offS, offD, N, NB);
  scanC_k<<<2 * NB, 1024, 0, stream>>>(degS, degD, bsumx, offS, offD, curS, curD, N, NB);
  scatter_k<<<2048, 256, 0, stream>>>(ei, wm, curS, curD, csw, csds, csdw, E);

  gemm1_k<<<(N + 31) / 32, 256, 0, stream>>>(x, l1w, l1b, x1q1, N);
  node_q1_k<<<(N + 3) / 4, 256, 0, stream>>>(x1q1, offS, csw, pmaxk, pmink, nmaxk, nmink, zflag, g, N);
  msg1_k<<<(N + 3) / 4, 256, 0, stream>>>(x1q1, h, offD, csds, csdw, g, N);
  gemm2_k<<<(N * 16 + 255) / 256, 256, 0, stream>>>(h, l2w, l2b, x2q2, N);
  node_q2_k<<<(N + 3) / 4, 256, 0, stream>>>(x2q2, offS, csw, pmaxk, pmink, nmaxk, nmink, zflag, g, N);
  msg2_k<<<(N + 3) / 4, 256, 0, stream>>>(x2q2, out, offD, csds, csdw, g, N);
}

// Round 2
// 1632.986 us; speedup vs baseline: 1.5717x; 1.5717x over previous
//
#include <hip/hip_runtime.h>

// CurvGN 2-layer graph net, N=100k nodes, E=3.2M edges, 256->64->16.
// Algebra: edge-MLP logits = w_mul[e] * (w>0 ? gpos[i] : gneg[i]) + b2[i];
// b2 cancels in per-src segment softmax. Segment max from per-src w endpoints
// (computed in node_q1 via lane-parallel scan, reused in node_q2).
// out[d][i] = sum_e exp(w_e*g_i) * q[src][i],  q = x*exp(-m)/(den+1e-16).

static __device__ __forceinline__ int ld_idx(const void* ei, long long pos, int is64) {
  return is64 ? (int)((const long long*)ei)[pos] : ((const int*)ei)[pos];
}

// ---- K1: collapse edge MLPs: g[0:64]=gpos1 g[64:128]=gneg1 g[128:144]=gpos2 g[144:160]=gneg2
__global__ void gvec_k(const float* __restrict__ w1a, const float* __restrict__ w2a,
                       const float* __restrict__ w1b, const float* __restrict__ w2b,
                       float* __restrict__ g) {
  int i = threadIdx.x;
  if (i < 64) {
    float sp = 0.f, sn = 0.f;
    for (int j = 0; j < 64; ++j) {
      float a = w1a[j], b = w2a[i * 64 + j], ab = a * b;
      sp += ab * (a > 0.f ? 1.f : 0.2f);
      sn += ab * (a < 0.f ? 1.f : 0.2f);
    }
    g[i] = sp; g[64 + i] = sn;
  }
  if (i < 16) {
    float sp = 0.f, sn = 0.f;
    for (int j = 0; j < 16; ++j) {
      float a = w1b[j], b = w2b[i * 16 + j], ab = a * b;
      sp += ab * (a > 0.f ? 1.f : 0.2f);
      sn += ab * (a < 0.f ? 1.f : 0.2f);
    }
    g[128 + i] = sp; g[144 + i] = sn;
  }
}

// ---- K2: degree histograms only (endpoint atomics removed — done in node_q1)
__global__ void edge_stats_k(const void* __restrict__ ei, int* degS, int* degD, int E) {
  __shared__ int s64;
  if (threadIdx.x == 0) {
    const unsigned* u = (const unsigned*)ei;
    unsigned o = 0;
    int lim = (2 * E < 32) ? 2 * E : 32;
    for (int t = 1; t < lim; t += 2) o |= u[t];
    s64 = (o == 0u);   // int64 little-endian: high words of small nonneg values are 0
  }
  __syncthreads();
  int is64 = s64;
  long long stride = (long long)gridDim.x * blockDim.x;
  for (long long e = (long long)blockIdx.x * blockDim.x + threadIdx.x; e < E; e += stride) {
    int s = ld_idx(ei, e, is64);
    int d = ld_idx(ei, e + E, is64);
    atomicAdd(&degS[s], 1);
    atomicAdd(&degD[d], 1);
  }
}

// ---- scan (3 kernels); handles both deg arrays (a = blockIdx / NB)
__global__ void scanA_k(const int* __restrict__ degS, const int* __restrict__ degD,
                        int* __restrict__ bsum, int N, int NB) {
  int b = blockIdx.x, a = b / NB, bb = b % NB;
  const int* deg = a ? degD : degS;
  int i = bb * 1024 + threadIdx.x;
  int v = (i < N) ? deg[i] : 0;
  int lane = threadIdx.x & 63, wid = threadIdx.x >> 6;
  #pragma unroll
  for (int d = 32; d > 0; d >>= 1) v += __shfl_xor(v, d);
  __shared__ int ws_[16];
  if (lane == 0) ws_[wid] = v;
  __syncthreads();
  if (threadIdx.x == 0) {
    int s = 0;
    for (int t = 0; t < 16; ++t) s += ws_[t];
    bsum[a * 256 + bb] = s;
  }
}
__global__ void scanB_k(const int* __restrict__ bsum, int* __restrict__ bsumx,
                        int* offS, int* offD, int N, int NB) {
  for (int a = 0; a < 2; ++a) {
    int c = 0;
    for (int b = 0; b < NB; ++b) { bsumx[a * 256 + b] = c; c += bsum[a * 256 + b]; }
    (a ? offD : offS)[N] = c;
  }
}
__global__ void scanC_k(const int* __restrict__ degS, const int* __restrict__ degD,
                        const int* __restrict__ bsumx,
                        int* offS, int* offD, int* curS, int* curD, int N, int NB) {
  int b = blockIdx.x, a = b / NB, bb = b % NB;
  const int* deg = a ? degD : degS;
  int* off = a ? offD : offS;
  int* cur = a ? curD : curS;
  int i = bb * 1024 + threadIdx.x;
  int v = (i < N) ? deg[i] : 0;
  int lane = threadIdx.x & 63, wid = threadIdx.x >> 6;
  int x = v;
  #pragma unroll
  for (int d = 1; d < 64; d <<= 1) { int t = __shfl_up(x, d); if (lane >= d) x += t; }
  __shared__ int ws_[16];
  if (lane == 63) ws_[wid] = x;
  __syncthreads();
  if (wid == 0) {
    int s = (lane < 16) ? ws_[lane] : 0;
    #pragma unroll
    for (int d = 1; d < 16; d <<= 1) { int t = __shfl_up(s, d); if (lane >= d) s += t; }
    if (lane < 16) ws_[lane] = s;
  }
  __syncthreads();
  int add = (wid ? ws_[wid - 1] : 0) + bsumx[a * 256 + bb];
  if (i < N) { int ex = add + x - v; off[i] = ex; cur[i] = ex; }
}

// ---- K4: scatter into CSR (order within a segment is irrelevant)
__global__ void scatter_k(const void* __restrict__ ei, const float* __restrict__ wm,
                          int* curS, int* curD,
                          float* __restrict__ csw, int* __restrict__ csds, float* __restrict__ csdw,
                          int E) {
  __shared__ int s64;
  if (threadIdx.x == 0) {
    const unsigned* u = (const unsigned*)ei;
    unsigned o = 0;
    int lim = (2 * E < 32) ? 2 * E : 32;
    for (int t = 1; t < lim; t += 2) o |= u[t];
    s64 = (o == 0u);
  }
  __syncthreads();
  int is64 = s64;
  long long stride = (long long)gridDim.x * blockDim.x;
  for (long long e = (long long)blockIdx.x * blockDim.x + threadIdx.x; e < E; e += stride) {
    int s = ld_idx(ei, e, is64);
    int d = ld_idx(ei, e + E, is64);
    float w = wm[e];
    int ps = atomicAdd(&curS[s], 1);
    csw[ps] = w;
    int pd = atomicAdd(&curD[d], 1);
    csds[pd] = s;
    csdw[pd] = w;
  }
}

// ---- K5: x1 = x @ lin1_w.T + b   (N x 256) x (64 x 256)^T -> N x 64
// Register-blocked tile GEMM: 128 rows x 64 cols per block, K-step 32.
// LDS 27.6KB -> ~5 blocks/CU; coalesced float4 global loads; 32 outputs/thread.
__global__ __launch_bounds__(256) void gemm1_k(const float* __restrict__ x,
                                               const float* __restrict__ W,
                                               const float* __restrict__ b,
                                               float* __restrict__ x1, int N) {
  __shared__ __align__(16) float Al[128 * 36];   // row stride 36: float4-aligned, breaks pow2
  __shared__ __align__(16) float Bl[64 * 36];
  int t = threadIdx.x;
  int n0 = blockIdx.x * 128;
  int tm = t & 31, tc = t >> 5;       // rows {tm,tm+32,tm+64,tm+96}, cols tc*8..tc*8+7
  int lr = t >> 3, lc = (t & 7) * 4;  // staging coords
  float acc[4][8];
  #pragma unroll
  for (int j = 0; j < 4; ++j)
    #pragma unroll
    for (int jj = 0; jj < 8; ++jj) acc[j][jj] = 0.f;

  for (int k0 = 0; k0 < 256; k0 += 32) {
    #pragma unroll
    for (int l = 0; l < 4; ++l) {
      int row = lr + l * 32;
      int n = n0 + row;
      float4 v = (n < N) ? *(const float4*)&x[(size_t)n * 256 + k0 + lc]
                         : make_float4(0.f, 0.f, 0.f, 0.f);
      *(float4*)&Al[row * 36 + lc] = v;
    }
    #pragma unroll
    for (int l = 0; l < 2; ++l) {
      int row = lr + l * 32;
      *(float4*)&Bl[row * 36 + lc] = *(const float4*)&W[row * 256 + k0 + lc];
    }
    __syncthreads();
    #pragma unroll
    for (int k4 = 0; k4 < 8; ++k4) {
      float4 a0 = *(const float4*)&Al[tm * 36 + k4 * 4];
      float4 a1 = *(const float4*)&Al[(tm + 32) * 36 + k4 * 4];
      float4 a2 = *(const float4*)&Al[(tm + 64) * 36 + k4 * 4];
      float4 a3 = *(const float4*)&Al[(tm + 96) * 36 + k4 * 4];
      #pragma unroll
      for (int jj = 0; jj < 8; ++jj) {
        float4 bv = *(const float4*)&Bl[(tc * 8 + jj) * 36 + k4 * 4];
        acc[0][jj] += a0.x * bv.x + a0.y * bv.y + a0.z * bv.z + a0.w * bv.w;
        acc[1][jj] += a1.x * bv.x + a1.y * bv.y + a1.z * bv.z + a1.w * bv.w;
        acc[2][jj] += a2.x * bv.x + a2.y * bv.y + a2.z * bv.z + a2.w * bv.w;
        acc[3][jj] += a3.x * bv.x + a3.y * bv.y + a3.z * bv.z + a3.w * bv.w;
      }
    }
    __syncthreads();
  }
  float bb0 = b[tc * 8 + 0], bb1 = b[tc * 8 + 1], bb2 = b[tc * 8 + 2], bb3 = b[tc * 8 + 3];
  float bb4 = b[tc * 8 + 4], bb5 = b[tc * 8 + 5], bb6 = b[tc * 8 + 6], bb7 = b[tc * 8 + 7];
  #pragma unroll
  for (int j = 0; j < 4; ++j) {
    int n = n0 + tm + j * 32;
    if (n < N) {
      float4 o0 = make_float4(acc[j][0] + bb0, acc[j][1] + bb1, acc[j][2] + bb2, acc[j][3] + bb3);
      float4 o1 = make_float4(acc[j][4] + bb4, acc[j][5] + bb5, acc[j][6] + bb6, acc[j][7] + bb7);
      *(float4*)&x1[(size_t)n * 64 + tc * 8] = o0;
      *(float4*)&x1[(size_t)n * 64 + tc * 8 + 4] = o1;
    }
  }
}

// ---- K6: q1 = x1 * exp(-m)/(den+1e-16), one wave per src node, lane = channel.
// Phase 1: lane-parallel coalesced endpoint scan (+store for node_q2 reuse).
// Phase 2: den via register-shuffle broadcast (no serial memory loads).
__global__ void node_q1_k(float* __restrict__ x1q1, const int* __restrict__ offS,
                          const float* __restrict__ csw,
                          float4* __restrict__ epw, int* __restrict__ epz,
                          const float* __restrict__ g, int N) {
  int wv = (int)(((long long)blockIdx.x * blockDim.x + threadIdx.x) >> 6);
  if (wv >= N) return;
  int lane = threadIdx.x & 63;
  int s = wv;
  int beg = offS[s], end = offS[s + 1];
  if (beg == end) return;  // empty segment: q1[s] never read
  // phase 1: per-sign endpoints
  float wpmax = -3.0e38f, wpmin = 3.0e38f, wnmax = -3.0e38f, wnmin = 3.0e38f;
  int zf = 0;
  for (int t = beg + lane; t < end; t += 64) {
    float w = csw[t];
    if (w > 0.f)      { wpmax = fmaxf(wpmax, w); wpmin = fminf(wpmin, w); }
    else if (w < 0.f) { wnmax = fmaxf(wnmax, w); wnmin = fminf(wnmin, w); }
    else zf = 1;
  }
  #pragma unroll
  for (int d = 1; d < 64; d <<= 1) {
    wpmax = fmaxf(wpmax, __shfl_xor(wpmax, d));
    wpmin = fminf(wpmin, __shfl_xor(wpmin, d));
    wnmax = fmaxf(wnmax, __shfl_xor(wnmax, d));
    wnmin = fminf(wnmin, __shfl_xor(wnmin, d));
    zf |= __shfl_xor(zf, d);
  }
  if (lane == 0) { epw[s] = make_float4(wpmax, wpmin, wnmax, wnmin); epz[s] = zf; }
  float gp = g[lane], gn = g[64 + lane];
  float m = -3.0e38f;
  if (wpmax > -1.0e38f) m = fmaxf(m, gp > 0.f ? wpmax * gp : wpmin * gp);
  if (wnmax > -1.0e38f) m = fmaxf(m, gn > 0.f ? wnmax * gn : wnmin * gn);
  if (zf) m = fmaxf(m, 0.f);
  // phase 2: den
  float den = 0.f;
  for (int t0 = beg; t0 < end; t0 += 64) {
    int nv = min(64, end - t0);
    float wl = (t0 + lane < end) ? csw[t0 + lane] : 0.f;
    for (int j = 0; j < nv; ++j) {
      float w = __shfl(wl, j);
      den += __expf(w * (w > 0.f ? gp : gn) - m);
    }
  }
  int o = s * 64 + lane;
  x1q1[o] = x1q1[o] * (__expf(-m) / (den + 1e-16f));
}

// ---- K7: h[d] = elu( sum_in exp(w*g)*q1[src] ), one wave per dst node.
// (s,w) pairs loaded coalesced per 64-chunk, broadcast via shfl.
__global__ void msg1_k(const float* __restrict__ q1, float* __restrict__ h,
                       const int* __restrict__ offD, const int* __restrict__ csds,
                       const float* __restrict__ csdw, const float* __restrict__ g, int N) {
  int wv = (int)(((long long)blockIdx.x * blockDim.x + threadIdx.x) >> 6);
  if (wv >= N) return;
  int lane = threadIdx.x & 63;
  int d = wv;
  int beg = offD[d], end = offD[d + 1];
  float gp = g[lane], gn = g[64 + lane];
  float acc = 0.f;
  for (int t0 = beg; t0 < end; t0 += 64) {
    int nv = min(64, end - t0);
    int   sl = (t0 + lane < end) ? csds[t0 + lane] : 0;
    float wl = (t0 + lane < end) ? csdw[t0 + lane] : 0.f;
    for (int j = 0; j < nv; ++j) {
      int s = __shfl(sl, j);
      float w = __shfl(wl, j);
      acc += __expf(w * (w > 0.f ? gp : gn)) * q1[s * 64 + lane];
    }
  }
  h[d * 64 + lane] = acc > 0.f ? acc : (__expf(acc) - 1.f);
}

// ---- K5b: x2 = h @ lin2_w.T + b   (N x 64) x (16 x 64)^T -> N x 16
__global__ void gemm2_k(const float* __restrict__ h, const float* __restrict__ W,
                        const float* __restrict__ b, float* __restrict__ x2, int N) {
  long long idx = (long long)blockIdx.x * blockDim.x + threadIdx.x;
  if (idx >= (long long)N * 16) return;
  int n = (int)(idx >> 4), i = (int)(idx & 15);
  const float* hr = h + (long long)n * 64;
  const float* wr = W + i * 64;
  float acc = 0.f;
  #pragma unroll
  for (int k = 0; k < 64; k += 4) {
    float4 a = *(const float4*)&hr[k];
    float4 w4 = *(const float4*)&wr[k];
    acc += a.x * w4.x + a.y * w4.y + a.z * w4.z + a.w * w4.w;
  }
  x2[idx] = acc + b[i];
}

// ---- K8: q2 (16 channels, 4-way edge-parallel), endpoints reused from node_q1
__global__ void node_q2_k(float* __restrict__ x2q2, const int* __restrict__ offS,
                          const float* __restrict__ csw,
                          const float4* __restrict__ epw, const int* __restrict__ epz,
                          const float* __restrict__ g, int N) {
  int wv = (int)(((long long)blockIdx.x * blockDim.x + threadIdx.x) >> 6);
  if (wv >= N) return;
  int lane = threadIdx.x & 63, i = lane & 15, p = lane >> 4;
  int s = wv;
  int beg = offS[s], end = offS[s + 1];
  if (beg == end) return;  // q2[s] never read
  float4 ep = epw[s];
  int zf = epz[s];
  float gp = g[128 + i], gn = g[144 + i];
  float m = -3.0e38f;
  if (ep.x > -1.0e38f) m = fmaxf(m, gp > 0.f ? ep.x * gp : ep.y * gp);
  if (ep.z > -1.0e38f) m = fmaxf(m, gn > 0.f ? ep.z * gn : ep.w * gn);
  if (zf) m = fmaxf(m, 0.f);
  float den = 0.f;
  for (int t0 = beg; t0 < end; t0 += 64) {
    int nv = min(64, end - t0);
    float wl = (t0 + lane < end) ? csw[t0 + lane] : 0.f;
    for (int j = p; j < nv; j += 4) {
      float w = __shfl(wl, j);
      den += __expf(w * (w > 0.f ? gp : gn) - m);
    }
  }
  den += __shfl_xor(den, 16);
  den += __shfl_xor(den, 32);
  if (p == 0) {
    int o = s * 16 + i;
    x2q2[o] = x2q2[o] * (__expf(-m) / (den + 1e-16f));
  }
}

// ---- K9: out2 aggregation + log_softmax fused
__global__ void msg2_k(const float* __restrict__ q2, float* __restrict__ out,
                       const int* __restrict__ offD, const int* __restrict__ csds,
                       const float* __restrict__ csdw, const float* __restrict__ g, int N) {
  int wv = (int)(((long long)blockIdx.x * blockDim.x + threadIdx.x) >> 6);
  if (wv >= N) return;
  int lane = threadIdx.x & 63, i = lane & 15, p = lane >> 4;
  int d = wv;
  int beg = offD[d], end = offD[d + 1];
  float gp = g[128 + i], gn = g[144 + i];
  float accp = 0.f;
  for (int t0 = beg; t0 < end; t0 += 64) {
    int nv = min(64, end - t0);
    int   sl = (t0 + lane < end) ? csds[t0 + lane] : 0;
    float wl = (t0 + lane < end) ? csdw[t0 + lane] : 0.f;
    for (int j = p; j < nv; j += 4) {
      int s = __shfl(sl, j);
      float w = __shfl(wl, j);
      accp += __expf(w * (w > 0.f ? gp : gn)) * q2[s * 16 + i];
    }
  }
  float acc = accp;
  acc += __shfl_xor(acc, 16);
  acc += __shfl_xor(acc, 32);
  // log_softmax across the 16 channels (xor<16 stays within the p-group)
  float mx = acc;
  #pragma unroll
  for (int d2 = 1; d2 < 16; d2 <<= 1) mx = fmaxf(mx, __shfl_xor(mx, d2));
  float se = __expf(acc - mx);
  #pragma unroll
  for (int d2 = 1; d2 < 16; d2 <<= 1) se += __shfl_xor(se, d2);
  float ls = acc - mx - __logf(se);
  if (p == 0) out[d * 16 + i] = ls;
}

extern "C" void kernel_launch(void* const* d_in, const int* in_sizes, int n_in,
                              void* d_out, int out_size, void* d_ws, size_t ws_size,
                              hipStream_t stream) {
  const float* x    = (const float*)d_in[0];
  const void*  ei   = d_in[1];
  const float* wm   = (const float*)d_in[2];
  const float* l1w  = (const float*)d_in[3];
  const float* l1b  = (const float*)d_in[4];
  const float* m1w1 = (const float*)d_in[5];
  const float* m1w2 = (const float*)d_in[6];
  const float* l2w  = (const float*)d_in[8];
  const float* l2b  = (const float*)d_in[9];
  const float* m2w1 = (const float*)d_in[10];
  const float* m2w2 = (const float*)d_in[11];
  // mlp*_b2 (d_in[7], d_in[12]) cancel in the segment softmax — unused.

  int N = in_sizes[0] / 256;
  int E = in_sizes[2];
  float* out = (float*)d_out;

  char* base = (char*)d_ws;
  size_t off = 0;
  auto alloc = [&](size_t bytes) -> char* {
    char* p = base + off;
    off = (off + bytes + 255) & ~(size_t)255;
    return p;
  };
  char* zbeg = base + off;
  int* degS = (int*)alloc((size_t)N * 4);
  int* degD = (int*)alloc((size_t)N * 4);
  char* zend = base + off;
  int* offS  = (int*)alloc((size_t)(N + 1) * 4);
  int* offD  = (int*)alloc((size_t)(N + 1) * 4);
  int* curS  = (int*)alloc((size_t)N * 4);
  int* curD  = (int*)alloc((size_t)N * 4);
  float4* epw = (float4*)alloc((size_t)N * 16);
  int*    epz = (int*)alloc((size_t)N * 4);
  float* g   = (float*)alloc(1024);
  int* bsum  = (int*)alloc(2 * 256 * 4);
  int* bsumx = (int*)alloc(2 * 256 * 4);
  float* csw  = (float*)alloc((size_t)E * 4);
  int*   csds = (int*)alloc((size_t)E * 4);
  float* csdw = (float*)alloc((size_t)E * 4);
  float* x1q1 = (float*)alloc((size_t)N * 64 * 4);   // x1, then q1 in-place
  float* h    = (float*)alloc((size_t)N * 64 * 4);
  float* x2q2 = (float*)alloc((size_t)N * 16 * 4);   // x2, then q2 in-place

  hipMemsetAsync(zbeg, 0, (size_t)(zend - zbeg), stream);

  gvec_k<<<1, 64, 0, stream>>>(m1w1, m1w2, m2w1, m2w2, g);
  edge_stats_k<<<2048, 256, 0, stream>>>(ei, degS, degD, E);
  int NB = (N + 1023) / 1024;
  scanA_k<<<2 * NB, 1024, 0, stream>>>(degS, degD, bsum, N, NB);
  scanB_k<<<1, 1, 0, stream>>>(bsum, bsumx, offS, offD, N, NB);
  scanC_k<<<2 * NB, 1024, 0, stream>>>(degS, degD, bsumx, offS, offD, curS, curD, N, NB);
  scatter_k<<<2048, 256, 0, stream>>>(ei, wm, curS, curD, csw, csds, csdw, E);

  gemm1_k<<<(N + 127) / 128, 256, 0, stream>>>(x, l1w, l1b, x1q1, N);
  node_q1_k<<<(N + 3) / 4, 256, 0, stream>>>(x1q1, offS, csw, epw, epz, g, N);
  msg1_k<<<(N + 3) / 4, 256, 0, stream>>>(x1q1, h, offD, csds, csdw, g, N);
  gemm2_k<<<(N * 16 + 255) / 256, 256, 0, stream>>>(h, l2w, l2b, x2q2, N);
  node_q2_k<<<(N + 3) / 4, 256, 0, stream>>>(x2q2, offS, csw, epw, epz, g, N);
  msg2_k<<<(N + 3) / 4, 256, 0, stream>>>(x2q2, out, offD, csds, csdw, g, N);
}

// Round 3
// 1274.338 us; speedup vs baseline: 2.0140x; 1.2814x over previous
//
#include <hip/hip_runtime.h>

// CurvGN 2-layer graph net, N=100k nodes, E=3.2M edges, 256->64->16.
// Algebra: edge-MLP logits = w_mul[e] * (w>0 ? gpos[i] : gneg[i]) + b2[i];
// b2 cancels in per-src segment softmax. Segment max from per-src w endpoints.
// out[d][i] = sum_e exp(w_e*g_i) * q[src][i],  q = x*exp(-m)/(den+1e-16).
// Layer-2 softmax scale sc2 = exp(-m2)/(den2+eps) computed in node_q1's csw
// scan (same segments, different g), applied in gemm2 -> node_q2 eliminated.
// Scatter is XCD-partitioned: block r=blockIdx%8 only writes CSR entries for
// nodes in range r, so every CSR cache line is written by one XCD's L2 and
// evicts full (fixes 490MB -> ~45MB partial-line write traffic).

static __device__ __forceinline__ int ld_idx(const void* ei, long long pos, int is64) {
  return is64 ? (int)((const long long*)ei)[pos] : ((const int*)ei)[pos];
}

// ---- K1: collapse edge MLPs: g[0:64]=gpos1 g[64:128]=gneg1 g[128:144]=gpos2 g[144:160]=gneg2
__global__ void gvec_k(const float* __restrict__ w1a, const float* __restrict__ w2a,
                       const float* __restrict__ w1b, const float* __restrict__ w2b,
                       float* __restrict__ g) {
  int i = threadIdx.x;
  if (i < 64) {
    float sp = 0.f, sn = 0.f;
    for (int j = 0; j < 64; ++j) {
      float a = w1a[j], b = w2a[i * 64 + j], ab = a * b;
      sp += ab * (a > 0.f ? 1.f : 0.2f);
      sn += ab * (a < 0.f ? 1.f : 0.2f);
    }
    g[i] = sp; g[64 + i] = sn;
  }
  if (i < 16) {
    float sp = 0.f, sn = 0.f;
    for (int j = 0; j < 16; ++j) {
      float a = w1b[j], b = w2b[i * 16 + j], ab = a * b;
      sp += ab * (a > 0.f ? 1.f : 0.2f);
      sn += ab * (a < 0.f ? 1.f : 0.2f);
    }
    g[128 + i] = sp; g[144 + i] = sn;
  }
}

// ---- K2: degree histograms + packed int2 (s,d) staging copy
__global__ void edge_stats_k(const void* __restrict__ ei, int* degS, int* degD,
                             int2* __restrict__ sd32, int E) {
  __shared__ int s64;
  if (threadIdx.x == 0) {
    const unsigned* u = (const unsigned*)ei;
    unsigned o = 0;
    int lim = (2 * E < 32) ? 2 * E : 32;
    for (int t = 1; t < lim; t += 2) o |= u[t];
    s64 = (o == 0u);   // int64 little-endian: high words of small nonneg values are 0
  }
  __syncthreads();
  int is64 = s64;
  long long stride = (long long)gridDim.x * blockDim.x;
  for (long long e = (long long)blockIdx.x * blockDim.x + threadIdx.x; e < E; e += stride) {
    int s = ld_idx(ei, e, is64);
    int d = ld_idx(ei, e + E, is64);
    sd32[e] = make_int2(s, d);
    atomicAdd(&degS[s], 1);
    atomicAdd(&degD[d], 1);
  }
}

// ---- scan (3 kernels); handles both deg arrays (a = blockIdx / NB)
__global__ void scanA_k(const int* __restrict__ degS, const int* __restrict__ degD,
                        int* __restrict__ bsum, int N, int NB) {
  int b = blockIdx.x, a = b / NB, bb = b % NB;
  const int* deg = a ? degD : degS;
  int i = bb * 1024 + threadIdx.x;
  int v = (i < N) ? deg[i] : 0;
  int lane = threadIdx.x & 63, wid = threadIdx.x >> 6;
  #pragma unroll
  for (int d = 32; d > 0; d >>= 1) v += __shfl_xor(v, d);
  __shared__ int ws_[16];
  if (lane == 0) ws_[wid] = v;
  __syncthreads();
  if (threadIdx.x == 0) {
    int s = 0;
    for (int t = 0; t < 16; ++t) s += ws_[t];
    bsum[a * 256 + bb] = s;
  }
}
__global__ void scanB_k(const int* __restrict__ bsum, int* __restrict__ bsumx,
                        int* offS, int* offD, int N, int NB) {
  for (int a = 0; a < 2; ++a) {
    int c = 0;
    for (int b = 0; b < NB; ++b) { bsumx[a * 256 + b] = c; c += bsum[a * 256 + b]; }
    (a ? offD : offS)[N] = c;
  }
}
__global__ void scanC_k(const int* __restrict__ degS, const int* __restrict__ degD,
                        const int* __restrict__ bsumx,
                        int* offS, int* offD, int* curS, int* curD, int N, int NB) {
  int b = blockIdx.x, a = b / NB, bb = b % NB;
  const int* deg = a ? degD : degS;
  int* off = a ? offD : offS;
  int* cur = a ? curD : curS;
  int i = bb * 1024 + threadIdx.x;
  int v = (i < N) ? deg[i] : 0;
  int lane = threadIdx.x & 63, wid = threadIdx.x >> 6;
  int x = v;
  #pragma unroll
  for (int d = 1; d < 64; d <<= 1) { int t = __shfl_up(x, d); if (lane >= d) x += t; }
  __shared__ int ws_[16];
  if (lane == 63) ws_[wid] = x;
  __syncthreads();
  if (wid == 0) {
    int s = (lane < 16) ? ws_[lane] : 0;
    #pragma unroll
    for (int d = 1; d < 16; d <<= 1) { int t = __shfl_up(s, d); if (lane >= d) s += t; }
    if (lane < 16) ws_[lane] = s;
  }
  __syncthreads();
  int add = (wid ? ws_[wid - 1] : 0) + bsumx[a * 256 + bb];
  if (i < N) { int ex = add + x - v; off[i] = ex; cur[i] = ex; }
}

// ---- K4: XCD-partitioned scatter into CSR.
// r = blockIdx%8 (heuristic XCD); only scatters nodes in range r. Each chunk
// of edges is read by 8 blocks (LLC-served); writes stay XCD-local -> full lines.
#define SC_CHUNKS 512
__global__ void scatter_k(const int2* __restrict__ sd32, const float* __restrict__ wm,
                          int* curS, int* curD,
                          float* __restrict__ csw, uint2* __restrict__ csde,
                          int E, int N) {
  int r = blockIdx.x & 7;
  int cb = blockIdx.x >> 3;
  int chunk = (E + SC_CHUNKS - 1) / SC_CHUNKS;
  int ns8 = (N + 7) / 8;
  int lo = r * ns8;
  unsigned span = (unsigned)(min(N, lo + ns8) - lo);
  int e0 = cb * chunk, e1 = min(E, e0 + chunk);
  for (int e = e0 + (int)threadIdx.x; e < e1; e += 256) {
    int2 sd = sd32[e];
    bool ms = (unsigned)(sd.x - lo) < span;
    bool md = (unsigned)(sd.y - lo) < span;
    if (ms | md) {
      float w = wm[e];
      if (ms) { int ps = atomicAdd(&curS[sd.x], 1); csw[ps] = w; }
      if (md) { int pd = atomicAdd(&curD[sd.y], 1);
                csde[pd] = make_uint2((unsigned)sd.x, __float_as_uint(w)); }
    }
  }
}

// ---- K5: x1 = x @ lin1_w.T + b   (N x 256) x (64 x 256)^T -> N x 64
__global__ __launch_bounds__(256) void gemm1_k(const float* __restrict__ x,
                                               const float* __restrict__ W,
                                               const float* __restrict__ b,
                                               float* __restrict__ x1, int N) {
  __shared__ __align__(16) float Al[128 * 36];
  __shared__ __align__(16) float Bl[64 * 36];
  int t = threadIdx.x;
  int n0 = blockIdx.x * 128;
  int tm = t & 31, tc = t >> 5;
  int lr = t >> 3, lc = (t & 7) * 4;
  float acc[4][8];
  #pragma unroll
  for (int j = 0; j < 4; ++j)
    #pragma unroll
    for (int jj = 0; jj < 8; ++jj) acc[j][jj] = 0.f;

  for (int k0 = 0; k0 < 256; k0 += 32) {
    #pragma unroll
    for (int l = 0; l < 4; ++l) {
      int row = lr + l * 32;
      int n = n0 + row;
      float4 v = (n < N) ? *(const float4*)&x[(size_t)n * 256 + k0 + lc]
                         : make_float4(0.f, 0.f, 0.f, 0.f);
      *(float4*)&Al[row * 36 + lc] = v;
    }
    #pragma unroll
    for (int l = 0; l < 2; ++l) {
      int row = lr + l * 32;
      *(float4*)&Bl[row * 36 + lc] = *(const float4*)&W[row * 256 + k0 + lc];
    }
    __syncthreads();
    #pragma unroll
    for (int k4 = 0; k4 < 8; ++k4) {
      float4 a0 = *(const float4*)&Al[tm * 36 + k4 * 4];
      float4 a1 = *(const float4*)&Al[(tm + 32) * 36 + k4 * 4];
      float4 a2 = *(const float4*)&Al[(tm + 64) * 36 + k4 * 4];
      float4 a3 = *(const float4*)&Al[(tm + 96) * 36 + k4 * 4];
      #pragma unroll
      for (int jj = 0; jj < 8; ++jj) {
        float4 bv = *(const float4*)&Bl[(tc * 8 + jj) * 36 + k4 * 4];
        acc[0][jj] += a0.x * bv.x + a0.y * bv.y + a0.z * bv.z + a0.w * bv.w;
        acc[1][jj] += a1.x * bv.x + a1.y * bv.y + a1.z * bv.z + a1.w * bv.w;
        acc[2][jj] += a2.x * bv.x + a2.y * bv.y + a2.z * bv.z + a2.w * bv.w;
        acc[3][jj] += a3.x * bv.x + a3.y * bv.y + a3.z * bv.z + a3.w * bv.w;
      }
    }
    __syncthreads();
  }
  float bb0 = b[tc * 8 + 0], bb1 = b[tc * 8 + 1], bb2 = b[tc * 8 + 2], bb3 = b[tc * 8 + 3];
  float bb4 = b[tc * 8 + 4], bb5 = b[tc * 8 + 5], bb6 = b[tc * 8 + 6], bb7 = b[tc * 8 + 7];
  #pragma unroll
  for (int j = 0; j < 4; ++j) {
    int n = n0 + tm + j * 32;
    if (n < N) {
      float4 o0 = make_float4(acc[j][0] + bb0, acc[j][1] + bb1, acc[j][2] + bb2, acc[j][3] + bb3);
      float4 o1 = make_float4(acc[j][4] + bb4, acc[j][5] + bb5, acc[j][6] + bb6, acc[j][7] + bb7);
      *(float4*)&x1[(size_t)n * 64 + tc * 8] = o0;
      *(float4*)&x1[(size_t)n * 64 + tc * 8 + 4] = o1;
    }
  }
}

// ---- K6: q1 scale + layer-2 scale sc2, one wave per src node.
// Lane-parallel endpoint scan, then den1 (64ch, lane=i) and den2 (16ch,
// lane&15=i, duplicated across lane groups -- lanes<16 write sc2).
__global__ void node_q1_k(float* __restrict__ x1q1, const int* __restrict__ offS,
                          const float* __restrict__ csw, float* __restrict__ sc2,
                          const float* __restrict__ g, int N) {
  int wv = (int)(((long long)blockIdx.x * blockDim.x + threadIdx.x) >> 6);
  if (wv >= N) return;
  int lane = threadIdx.x & 63;
  int s = wv;
  int beg = offS[s], end = offS[s + 1];
  if (beg == end) return;  // empty segment: q1[s]/sc2[s] never read
  // endpoints
  float wpmax = -3.0e38f, wpmin = 3.0e38f, wnmax = -3.0e38f, wnmin = 3.0e38f;
  int zf = 0;
  for (int t = beg + lane; t < end; t += 64) {
    float w = csw[t];
    if (w > 0.f)      { wpmax = fmaxf(wpmax, w); wpmin = fminf(wpmin, w); }
    else if (w < 0.f) { wnmax = fmaxf(wnmax, w); wnmin = fminf(wnmin, w); }
    else zf = 1;
  }
  #pragma unroll
  for (int d = 1; d < 64; d <<= 1) {
    wpmax = fmaxf(wpmax, __shfl_xor(wpmax, d));
    wpmin = fminf(wpmin, __shfl_xor(wpmin, d));
    wnmax = fmaxf(wnmax, __shfl_xor(wnmax, d));
    wnmin = fminf(wnmin, __shfl_xor(wnmin, d));
    zf |= __shfl_xor(zf, d);
  }
  int li = lane & 15;
  float gp = g[lane], gn = g[64 + lane];
  float gp2 = g[128 + li], gn2 = g[144 + li];
  float m = -3.0e38f, m2 = -3.0e38f;
  if (wpmax > -1.0e38f) { m = fmaxf(m, gp > 0.f ? wpmax * gp : wpmin * gp);
                          m2 = fmaxf(m2, gp2 > 0.f ? wpmax * gp2 : wpmin * gp2); }
  if (wnmax > -1.0e38f) { m = fmaxf(m, gn > 0.f ? wnmax * gn : wnmin * gn);
                          m2 = fmaxf(m2, gn2 > 0.f ? wnmax * gn2 : wnmin * gn2); }
  if (zf) { m = fmaxf(m, 0.f); m2 = fmaxf(m2, 0.f); }
  float den = 0.f, den2 = 0.f;
  for (int t0 = beg; t0 < end; t0 += 64) {
    int nv = min(64, end - t0);
    float wl = (t0 + lane < end) ? csw[t0 + lane] : 0.f;
    for (int j = 0; j < nv; ++j) {
      float w = __shfl(wl, j);
      den  += __expf(w * (w > 0.f ? gp  : gn)  - m);
      den2 += __expf(w * (w > 0.f ? gp2 : gn2) - m2);
    }
  }
  int o = s * 64 + lane;
  x1q1[o] = x1q1[o] * (__expf(-m) / (den + 1e-16f));
  if (lane < 16) sc2[s * 16 + li] = __expf(-m2) / (den2 + 1e-16f);
}

// ---- K7: h[d] = elu( sum_in exp(w*g)*q1[src] ), one wave per dst node.
__global__ void msg1_k(const float* __restrict__ q1, float* __restrict__ h,
                       const int* __restrict__ offD, const uint2* __restrict__ csde,
                       const float* __restrict__ g, int N) {
  int wv = (int)(((long long)blockIdx.x * blockDim.x + threadIdx.x) >> 6);
  if (wv >= N) return;
  int lane = threadIdx.x & 63;
  int d = wv;
  int beg = offD[d], end = offD[d + 1];
  float gp = g[lane], gn = g[64 + lane];
  float acc = 0.f;
  for (int t0 = beg; t0 < end; t0 += 64) {
    int nv = min(64, end - t0);
    uint2 ew = (t0 + lane < end) ? csde[t0 + lane] : make_uint2(0u, 0u);
    int sl = (int)ew.x;
    float wl = __uint_as_float(ew.y);
    for (int j = 0; j < nv; ++j) {
      int s = __shfl(sl, j);
      float w = __shfl(wl, j);
      acc += __expf(w * (w > 0.f ? gp : gn)) * q1[s * 64 + lane];
    }
  }
  h[d * 64 + lane] = acc > 0.f ? acc : (__expf(acc) - 1.f);
}

// ---- K5b: x2q2 = (h @ lin2_w.T + b) * sc2   (q2 directly)
__global__ void gemm2_k(const float* __restrict__ h, const float* __restrict__ W,
                        const float* __restrict__ b, const float* __restrict__ sc2,
                        float* __restrict__ x2, int N) {
  long long idx = (long long)blockIdx.x * blockDim.x + threadIdx.x;
  if (idx >= (long long)N * 16) return;
  int n = (int)(idx >> 4), i = (int)(idx & 15);
  const float* hr = h + (long long)n * 64;
  const float* wr = W + i * 64;
  float acc = 0.f;
  #pragma unroll
  for (int k = 0; k < 64; k += 4) {
    float4 a = *(const float4*)&hr[k];
    float4 w4 = *(const float4*)&wr[k];
    acc += a.x * w4.x + a.y * w4.y + a.z * w4.z + a.w * w4.w;
  }
  x2[idx] = (acc + b[i]) * sc2[idx];
}

// ---- K9: out2 aggregation + log_softmax fused
__global__ void msg2_k(const float* __restrict__ q2, float* __restrict__ out,
                       const int* __restrict__ offD, const uint2* __restrict__ csde,
                       const float* __restrict__ g, int N) {
  int wv = (int)(((long long)blockIdx.x * blockDim.x + threadIdx.x) >> 6);
  if (wv >= N) return;
  int lane = threadIdx.x & 63, i = lane & 15, p = lane >> 4;
  int d = wv;
  int beg = offD[d], end = offD[d + 1];
  float gp = g[128 + i], gn = g[144 + i];
  float accp = 0.f;
  for (int t0 = beg; t0 < end; t0 += 64) {
    int nv = min(64, end - t0);
    uint2 ew = (t0 + lane < end) ? csde[t0 + lane] : make_uint2(0u, 0u);
    int sl = (int)ew.x;
    float wl = __uint_as_float(ew.y);
    for (int j = p; j < nv; j += 4) {
      int s = __shfl(sl, j);
      float w = __shfl(wl, j);
      accp += __expf(w * (w > 0.f ? gp : gn)) * q2[s * 16 + i];
    }
  }
  float acc = accp;
  acc += __shfl_xor(acc, 16);
  acc += __shfl_xor(acc, 32);
  float mx = acc;
  #pragma unroll
  for (int d2 = 1; d2 < 16; d2 <<= 1) mx = fmaxf(mx, __shfl_xor(mx, d2));
  float se = __expf(acc - mx);
  #pragma unroll
  for (int d2 = 1; d2 < 16; d2 <<= 1) se += __shfl_xor(se, d2);
  float ls = acc - mx - __logf(se);
  if (p == 0) out[d * 16 + i] = ls;
}

extern "C" void kernel_launch(void* const* d_in, const int* in_sizes, int n_in,
                              void* d_out, int out_size, void* d_ws, size_t ws_size,
                              hipStream_t stream) {
  const float* x    = (const float*)d_in[0];
  const void*  ei   = d_in[1];
  const float* wm   = (const float*)d_in[2];
  const float* l1w  = (const float*)d_in[3];
  const float* l1b  = (const float*)d_in[4];
  const float* m1w1 = (const float*)d_in[5];
  const float* m1w2 = (const float*)d_in[6];
  const float* l2w  = (const float*)d_in[8];
  const float* l2b  = (const float*)d_in[9];
  const float* m2w1 = (const float*)d_in[10];
  const float* m2w2 = (const float*)d_in[11];
  // mlp*_b2 (d_in[7], d_in[12]) cancel in the segment softmax — unused.

  int N = in_sizes[0] / 256;
  int E = in_sizes[2];
  float* out = (float*)d_out;

  char* base = (char*)d_ws;
  size_t off = 0;
  auto alloc = [&](size_t bytes) -> char* {
    char* p = base + off;
    off = (off + bytes + 255) & ~(size_t)255;
    return p;
  };
  char* zbeg = base + off;
  int* degS = (int*)alloc((size_t)N * 4);
  int* degD = (int*)alloc((size_t)N * 4);
  char* zend = base + off;
  int* offS  = (int*)alloc((size_t)(N + 1) * 4);
  int* offD  = (int*)alloc((size_t)(N + 1) * 4);
  int* curS  = (int*)alloc((size_t)N * 4);
  int* curD  = (int*)alloc((size_t)N * 4);
  float* sc2 = (float*)alloc((size_t)N * 16 * 4);
  float* g   = (float*)alloc(1024);
  int* bsum  = (int*)alloc(2 * 256 * 4);
  int* bsumx = (int*)alloc(2 * 256 * 4);
  int2*  sd32 = (int2*)alloc((size_t)E * 8);
  float* csw  = (float*)alloc((size_t)E * 4);
  uint2* csde = (uint2*)alloc((size_t)E * 8);
  float* x1q1 = (float*)alloc((size_t)N * 64 * 4);   // x1, then q1 in-place
  float* h    = (float*)alloc((size_t)N * 64 * 4);
  float* x2q2 = (float*)alloc((size_t)N * 16 * 4);   // q2 directly (scale fused)

  hipMemsetAsync(zbeg, 0, (size_t)(zend - zbeg), stream);

  gvec_k<<<1, 64, 0, stream>>>(m1w1, m1w2, m2w1, m2w2, g);
  edge_stats_k<<<2048, 256, 0, stream>>>(ei, degS, degD, sd32, E);
  int NB = (N + 1023) / 1024;
  scanA_k<<<2 * NB, 1024, 0, stream>>>(degS, degD, bsum, N, NB);
  scanB_k<<<1, 1, 0, stream>>>(bsum, bsumx, offS, offD, N, NB);
  scanC_k<<<2 * NB, 1024, 0, stream>>>(degS, degD, bsumx, offS, offD, curS, curD, N, NB);
  scatter_k<<<SC_CHUNKS * 8, 256, 0, stream>>>(sd32, wm, curS, curD, csw, csde, E, N);

  gemm1_k<<<(N + 127) / 128, 256, 0, stream>>>(x, l1w, l1b, x1q1, N);
  node_q1_k<<<(N + 3) / 4, 256, 0, stream>>>(x1q1, offS, csw, sc2, g, N);
  msg1_k<<<(N + 3) / 4, 256, 0, stream>>>(x1q1, h, offD, csde, g, N);
  gemm2_k<<<(N * 16 + 255) / 256, 256, 0, stream>>>(h, l2w, l2b, sc2, x2q2, N);
  msg2_k<<<(N + 3) / 4, 256, 0, stream>>>(x2q2, out, offD, csde, g, N);
}

// Round 5
// 1128.850 us; speedup vs baseline: 2.2735x; 1.1289x over previous
//
#include <hip/hip_runtime.h>

// CurvGN 2-layer graph net, N=100k nodes, E=3.2M edges, 256->64->16.
// Algebra: edge-MLP logits = w_mul[e] * (w>0 ? gpos[i] : gneg[i]) + b2[i];
// b2 cancels in per-src segment softmax. Segment max from per-src w endpoints.
// out[d][i] = sum_e exp(w_e*g_i) * q[src][i],  q = x*exp(-m)/(den+1e-16).
// Layer-2 scale sc2 computed in node_q1's csw scan, applied in gemm2.
// CSR build: edge_stats' degree atomicAdd returns each edge's rank within its
// segment -> scatter is ATOMIC-FREE: pos = off[node] + rank.
// R4 bug fixed: den2 must cover ALL edges per channel -> p-strided (j=p; j+=4)
// shfl-broadcast so the 4 lane-groups jointly cover every chunk position.

static __device__ __forceinline__ int ld_idx(const void* ei, long long pos, int is64) {
  return is64 ? (int)((const long long*)ei)[pos] : ((const int*)ei)[pos];
}

// ---- K1: collapse edge MLPs: g[0:64]=gpos1 g[64:128]=gneg1 g[128:144]=gpos2 g[144:160]=gneg2
__global__ void gvec_k(const float* __restrict__ w1a, const float* __restrict__ w2a,
                       const float* __restrict__ w1b, const float* __restrict__ w2b,
                       float* __restrict__ g) {
  int i = threadIdx.x;
  if (i < 64) {
    float sp = 0.f, sn = 0.f;
    for (int j = 0; j < 64; ++j) {
      float a = w1a[j], b = w2a[i * 64 + j], ab = a * b;
      sp += ab * (a > 0.f ? 1.f : 0.2f);
      sn += ab * (a < 0.f ? 1.f : 0.2f);
    }
    g[i] = sp; g[64 + i] = sn;
  }
  if (i < 16) {
    float sp = 0.f, sn = 0.f;
    for (int j = 0; j < 16; ++j) {
      float a = w1b[j], b = w2b[i * 16 + j], ab = a * b;
      sp += ab * (a > 0.f ? 1.f : 0.2f);
      sn += ab * (a < 0.f ? 1.f : 0.2f);
    }
    g[128 + i] = sp; g[144 + i] = sn;
  }
}

// ---- K2: degree histograms; atomic return values are per-edge ranks.
// One coalesced int4 store per edge: (s, d, rankS, rankD).
__global__ void edge_stats_k(const void* __restrict__ ei, int* degS, int* degD,
                             int4* __restrict__ sdrr, int E) {
  __shared__ int s64;
  if (threadIdx.x == 0) {
    const unsigned* u = (const unsigned*)ei;
    unsigned o = 0;
    int lim = (2 * E < 32) ? 2 * E : 32;
    for (int t = 1; t < lim; t += 2) o |= u[t];
    s64 = (o == 0u);   // int64 little-endian: high words of small nonneg values are 0
  }
  __syncthreads();
  int is64 = s64;
  long long stride = (long long)gridDim.x * blockDim.x;
  for (long long e = (long long)blockIdx.x * blockDim.x + threadIdx.x; e < E; e += stride) {
    int s = ld_idx(ei, e, is64);
    int d = ld_idx(ei, e + E, is64);
    int rs = atomicAdd(&degS[s], 1);
    int rd = atomicAdd(&degD[d], 1);
    sdrr[e] = make_int4(s, d, rs, rd);
  }
}

// ---- scan (3 kernels); handles both deg arrays (a = blockIdx / NB)
__global__ void scanA_k(const int* __restrict__ degS, const int* __restrict__ degD,
                        int* __restrict__ bsum, int N, int NB) {
  int b = blockIdx.x, a = b / NB, bb = b % NB;
  const int* deg = a ? degD : degS;
  int i = bb * 1024 + threadIdx.x;
  int v = (i < N) ? deg[i] : 0;
  int lane = threadIdx.x & 63, wid = threadIdx.x >> 6;
  #pragma unroll
  for (int d = 32; d > 0; d >>= 1) v += __shfl_xor(v, d);
  __shared__ int ws_[16];
  if (lane == 0) ws_[wid] = v;
  __syncthreads();
  if (threadIdx.x == 0) {
    int s = 0;
    for (int t = 0; t < 16; ++t) s += ws_[t];
    bsum[a * 256 + bb] = s;
  }
}
__global__ void scanB_k(const int* __restrict__ bsum, int* __restrict__ bsumx,
                        int* offS, int* offD, int N, int NB) {
  for (int a = 0; a < 2; ++a) {
    int c = 0;
    for (int b = 0; b < NB; ++b) { bsumx[a * 256 + b] = c; c += bsum[a * 256 + b]; }
    (a ? offD : offS)[N] = c;
  }
}
__global__ void scanC_k(const int* __restrict__ degS, const int* __restrict__ degD,
                        const int* __restrict__ bsumx,
                        int* offS, int* offD, int N, int NB) {
  int b = blockIdx.x, a = b / NB, bb = b % NB;
  const int* deg = a ? degD : degS;
  int* off = a ? offD : offS;
  int i = bb * 1024 + threadIdx.x;
  int v = (i < N) ? deg[i] : 0;
  int lane = threadIdx.x & 63, wid = threadIdx.x >> 6;
  int x = v;
  #pragma unroll
  for (int d = 1; d < 64; d <<= 1) { int t = __shfl_up(x, d); if (lane >= d) x += t; }
  __shared__ int ws_[16];
  if (lane == 63) ws_[wid] = x;
  __syncthreads();
  if (wid == 0) {
    int s = (lane < 16) ? ws_[lane] : 0;
    #pragma unroll
    for (int d = 1; d < 16; d <<= 1) { int t = __shfl_up(s, d); if (lane >= d) s += t; }
    if (lane < 16) ws_[lane] = s;
  }
  __syncthreads();
  int add = (wid ? ws_[wid - 1] : 0) + bsumx[a * 256 + bb];
  if (i < N) off[i] = add + x - v;
}

// ---- K4: atomic-free scatter into CSR: pos = off[node] + rank (from edge_stats)
__global__ void scatter_k(const int4* __restrict__ sdrr, const float* __restrict__ wm,
                          const int* __restrict__ offS, const int* __restrict__ offD,
                          float* __restrict__ csw, uint2* __restrict__ csde, int E) {
  int e = blockIdx.x * 256 + threadIdx.x;
  if (e >= E) return;
  int4 v = sdrr[e];
  float w = wm[e];
  csw[offS[v.x] + v.z] = w;
  csde[offD[v.y] + v.w] = make_uint2((unsigned)v.x, __float_as_uint(w));
}

// ---- K5: x1 = x @ lin1_w.T + b   (N x 256) x (64 x 256)^T -> N x 64
__global__ __launch_bounds__(256) void gemm1_k(const float* __restrict__ x,
                                               const float* __restrict__ W,
                                               const float* __restrict__ b,
                                               float* __restrict__ x1, int N) {
  __shared__ __align__(16) float Al[128 * 36];
  __shared__ __align__(16) float Bl[64 * 36];
  int t = threadIdx.x;
  int n0 = blockIdx.x * 128;
  int tm = t & 31, tc = t >> 5;
  int lr = t >> 3, lc = (t & 7) * 4;
  float acc[4][8];
  #pragma unroll
  for (int j = 0; j < 4; ++j)
    #pragma unroll
    for (int jj = 0; jj < 8; ++jj) acc[j][jj] = 0.f;

  for (int k0 = 0; k0 < 256; k0 += 32) {
    #pragma unroll
    for (int l = 0; l < 4; ++l) {
      int row = lr + l * 32;
      int n = n0 + row;
      float4 v = (n < N) ? *(const float4*)&x[(size_t)n * 256 + k0 + lc]
                         : make_float4(0.f, 0.f, 0.f, 0.f);
      *(float4*)&Al[row * 36 + lc] = v;
    }
    #pragma unroll
    for (int l = 0; l < 2; ++l) {
      int row = lr + l * 32;
      *(float4*)&Bl[row * 36 + lc] = *(const float4*)&W[row * 256 + k0 + lc];
    }
    __syncthreads();
    #pragma unroll
    for (int k4 = 0; k4 < 8; ++k4) {
      float4 a0 = *(const float4*)&Al[tm * 36 + k4 * 4];
      float4 a1 = *(const float4*)&Al[(tm + 32) * 36 + k4 * 4];
      float4 a2 = *(const float4*)&Al[(tm + 64) * 36 + k4 * 4];
      float4 a3 = *(const float4*)&Al[(tm + 96) * 36 + k4 * 4];
      #pragma unroll
      for (int jj = 0; jj < 8; ++jj) {
        float4 bv = *(const float4*)&Bl[(tc * 8 + jj) * 36 + k4 * 4];
        acc[0][jj] += a0.x * bv.x + a0.y * bv.y + a0.z * bv.z + a0.w * bv.w;
        acc[1][jj] += a1.x * bv.x + a1.y * bv.y + a1.z * bv.z + a1.w * bv.w;
        acc[2][jj] += a2.x * bv.x + a2.y * bv.y + a2.z * bv.z + a2.w * bv.w;
        acc[3][jj] += a3.x * bv.x + a3.y * bv.y + a3.z * bv.z + a3.w * bv.w;
      }
    }
    __syncthreads();
  }
  float bb0 = b[tc * 8 + 0], bb1 = b[tc * 8 + 1], bb2 = b[tc * 8 + 2], bb3 = b[tc * 8 + 3];
  float bb4 = b[tc * 8 + 4], bb5 = b[tc * 8 + 5], bb6 = b[tc * 8 + 6], bb7 = b[tc * 8 + 7];
  #pragma unroll
  for (int j = 0; j < 4; ++j) {
    int n = n0 + tm + j * 32;
    if (n < N) {
      float4 o0 = make_float4(acc[j][0] + bb0, acc[j][1] + bb1, acc[j][2] + bb2, acc[j][3] + bb3);
      float4 o1 = make_float4(acc[j][4] + bb4, acc[j][5] + bb5, acc[j][6] + bb6, acc[j][7] + bb7);
      *(float4*)&x1[(size_t)n * 64 + tc * 8] = o0;
      *(float4*)&x1[(size_t)n * 64 + tc * 8 + 4] = o1;
    }
  }
}

// ---- K6: q1 scale + layer-2 scale sc2, one wave per src node.
// den1: shfl-broadcast loop (64 channels x all edges).
// den2: p-strided broadcast (j=p; j+=4) -> the 4 lane-groups (p=lane>>4)
// jointly cover every chunk position; xor-{16,32} reduce at the end.
__global__ void node_q1_k(float* __restrict__ x1q1, const int* __restrict__ offS,
                          const float* __restrict__ csw, float* __restrict__ sc2,
                          const float* __restrict__ g, int N) {
  int wv = (int)(((long long)blockIdx.x * blockDim.x + threadIdx.x) >> 6);
  if (wv >= N) return;
  int lane = threadIdx.x & 63;
  int s = wv;
  int beg = offS[s], end = offS[s + 1];
  if (beg == end) return;  // empty segment: q1[s]/sc2[s] never read
  float wpmax = -3.0e38f, wpmin = 3.0e38f, wnmax = -3.0e38f, wnmin = 3.0e38f;
  int zf = 0;
  for (int t = beg + lane; t < end; t += 64) {
    float w = csw[t];
    if (w > 0.f)      { wpmax = fmaxf(wpmax, w); wpmin = fminf(wpmin, w); }
    else if (w < 0.f) { wnmax = fmaxf(wnmax, w); wnmin = fminf(wnmin, w); }
    else zf = 1;
  }
  #pragma unroll
  for (int d = 1; d < 64; d <<= 1) {
    wpmax = fmaxf(wpmax, __shfl_xor(wpmax, d));
    wpmin = fminf(wpmin, __shfl_xor(wpmin, d));
    wnmax = fmaxf(wnmax, __shfl_xor(wnmax, d));
    wnmin = fminf(wnmin, __shfl_xor(wnmin, d));
    zf |= __shfl_xor(zf, d);
  }
  int li = lane & 15, p = lane >> 4;
  float gp = g[lane], gn = g[64 + lane];
  float gp2 = g[128 + li], gn2 = g[144 + li];
  float m = -3.0e38f, m2 = -3.0e38f;
  if (wpmax > -1.0e38f) { m = fmaxf(m, gp > 0.f ? wpmax * gp : wpmin * gp);
                          m2 = fmaxf(m2, gp2 > 0.f ? wpmax * gp2 : wpmin * gp2); }
  if (wnmax > -1.0e38f) { m = fmaxf(m, gn > 0.f ? wnmax * gn : wnmin * gn);
                          m2 = fmaxf(m2, gn2 > 0.f ? wnmax * gn2 : wnmin * gn2); }
  if (zf) { m = fmaxf(m, 0.f); m2 = fmaxf(m2, 0.f); }
  float den = 0.f, den2p = 0.f;
  for (int t0 = beg; t0 < end; t0 += 64) {
    int nv = min(64, end - t0);
    float wl = (t0 + lane < end) ? csw[t0 + lane] : 0.f;
    for (int j = 0; j < nv; ++j) {
      float w = __shfl(wl, j);
      den += __expf(w * (w > 0.f ? gp : gn) - m);
    }
    for (int j = p; j < nv; j += 4) {
      float w = __shfl(wl, j);
      den2p += __expf(w * (w > 0.f ? gp2 : gn2) - m2);
    }
  }
  den2p += __shfl_xor(den2p, 16);
  den2p += __shfl_xor(den2p, 32);
  int o = s * 64 + lane;
  x1q1[o] = x1q1[o] * (__expf(-m) / (den + 1e-16f));
  if (lane < 16) sc2[s * 16 + li] = __expf(-m2) / (den2p + 1e-16f);
}

// ---- K7: h[d] = elu( sum_in exp(w*g)*q1[src] ), one wave per dst node.
// Unroll-2 + dual accumulators: keeps 2 independent gathers in flight.
__global__ void msg1_k(const float* __restrict__ q1, float* __restrict__ h,
                       const int* __restrict__ offD, const uint2* __restrict__ csde,
                       const float* __restrict__ g, int N) {
  int wv = (int)(((long long)blockIdx.x * blockDim.x + threadIdx.x) >> 6);
  if (wv >= N) return;
  int lane = threadIdx.x & 63;
  int d = wv;
  int beg = offD[d], end = offD[d + 1];
  float gp = g[lane], gn = g[64 + lane];
  float acc0 = 0.f, acc1 = 0.f;
  for (int t0 = beg; t0 < end; t0 += 64) {
    int nv = min(64, end - t0);
    uint2 ew = (t0 + lane < end) ? csde[t0 + lane] : make_uint2(0u, 0u);
    int sl = (int)ew.x;
    float wl = __uint_as_float(ew.y);
    int j = 0;
    for (; j + 1 < nv; j += 2) {
      int   sA = __shfl(sl, j);     float wA = __shfl(wl, j);
      int   sB = __shfl(sl, j + 1); float wB = __shfl(wl, j + 1);
      acc0 += __expf(wA * (wA > 0.f ? gp : gn)) * q1[sA * 64 + lane];
      acc1 += __expf(wB * (wB > 0.f ? gp : gn)) * q1[sB * 64 + lane];
    }
    if (j < nv) {
      int sA = __shfl(sl, j); float wA = __shfl(wl, j);
      acc0 += __expf(wA * (wA > 0.f ? gp : gn)) * q1[sA * 64 + lane];
    }
  }
  float acc = acc0 + acc1;
  h[d * 64 + lane] = acc > 0.f ? acc : (__expf(acc) - 1.f);
}

// ---- K5b: x2q2 = (h @ lin2_w.T + b) * sc2   (q2 directly)
__global__ void gemm2_k(const float* __restrict__ h, const float* __restrict__ W,
                        const float* __restrict__ b, const float* __restrict__ sc2,
                        float* __restrict__ x2, int N) {
  long long idx = (long long)blockIdx.x * blockDim.x + threadIdx.x;
  if (idx >= (long long)N * 16) return;
  int n = (int)(idx >> 4), i = (int)(idx & 15);
  const float* hr = h + (long long)n * 64;
  const float* wr = W + i * 64;
  float acc = 0.f;
  #pragma unroll
  for (int k = 0; k < 64; k += 4) {
    float4 a = *(const float4*)&hr[k];
    float4 w4 = *(const float4*)&wr[k];
    acc += a.x * w4.x + a.y * w4.y + a.z * w4.z + a.w * w4.w;
  }
  x2[idx] = (acc + b[i]) * sc2[idx];
}

// ---- K9: out2 aggregation + log_softmax fused
__global__ void msg2_k(const float* __restrict__ q2, float* __restrict__ out,
                       const int* __restrict__ offD, const uint2* __restrict__ csde,
                       const float* __restrict__ g, int N) {
  int wv = (int)(((long long)blockIdx.x * blockDim.x + threadIdx.x) >> 6);
  if (wv >= N) return;
  int lane = threadIdx.x & 63, i = lane & 15, p = lane >> 4;
  int d = wv;
  int beg = offD[d], end = offD[d + 1];
  float gp = g[128 + i], gn = g[144 + i];
  float accp = 0.f;
  for (int t0 = beg; t0 < end; t0 += 64) {
    int nv = min(64, end - t0);
    uint2 ew = (t0 + lane < end) ? csde[t0 + lane] : make_uint2(0u, 0u);
    int sl = (int)ew.x;
    float wl = __uint_as_float(ew.y);
    for (int j = p; j < nv; j += 4) {
      int s = __shfl(sl, j);
      float w = __shfl(wl, j);
      accp += __expf(w * (w > 0.f ? gp : gn)) * q2[s * 16 + i];
    }
  }
  float acc = accp;
  acc += __shfl_xor(acc, 16);
  acc += __shfl_xor(acc, 32);
  float mx = acc;
  #pragma unroll
  for (int d2 = 1; d2 < 16; d2 <<= 1) mx = fmaxf(mx, __shfl_xor(mx, d2));
  float se = __expf(acc - mx);
  #pragma unroll
  for (int d2 = 1; d2 < 16; d2 <<= 1) se += __shfl_xor(se, d2);
  float ls = acc - mx - __logf(se);
  if (p == 0) out[d * 16 + i] = ls;
}

extern "C" void kernel_launch(void* const* d_in, const int* in_sizes, int n_in,
                              void* d_out, int out_size, void* d_ws, size_t ws_size,
                              hipStream_t stream) {
  const float* x    = (const float*)d_in[0];
  const void*  ei   = d_in[1];
  const float* wm   = (const float*)d_in[2];
  const float* l1w  = (const float*)d_in[3];
  const float* l1b  = (const float*)d_in[4];
  const float* m1w1 = (const float*)d_in[5];
  const float* m1w2 = (const float*)d_in[6];
  const float* l2w  = (const float*)d_in[8];
  const float* l2b  = (const float*)d_in[9];
  const float* m2w1 = (const float*)d_in[10];
  const float* m2w2 = (const float*)d_in[11];
  // mlp*_b2 (d_in[7], d_in[12]) cancel in the segment softmax — unused.

  int N = in_sizes[0] / 256;
  int E = in_sizes[2];
  float* out = (float*)d_out;

  char* base = (char*)d_ws;
  size_t off = 0;
  auto alloc = [&](size_t bytes) -> char* {
    char* p = base + off;
    off = (off + bytes + 255) & ~(size_t)255;
    return p;
  };
  char* zbeg = base + off;
  int* degS = (int*)alloc((size_t)N * 4);
  int* degD = (int*)alloc((size_t)N * 4);
  char* zend = base + off;
  int* offS  = (int*)alloc((size_t)(N + 1) * 4);
  int* offD  = (int*)alloc((size_t)(N + 1) * 4);
  float* sc2 = (float*)alloc((size_t)N * 16 * 4);
  float* g   = (float*)alloc(1024);
  int* bsum  = (int*)alloc(2 * 256 * 4);
  int* bsumx = (int*)alloc(2 * 256 * 4);
  int4*  sdrr = (int4*)alloc((size_t)E * 16);
  float* csw  = (float*)alloc((size_t)E * 4);
  uint2* csde = (uint2*)alloc((size_t)E * 8);
  float* x1q1 = (float*)alloc((size_t)N * 64 * 4);   // x1, then q1 in-place
  float* h    = (float*)alloc((size_t)N * 64 * 4);
  float* x2q2 = (float*)alloc((size_t)N * 16 * 4);   // q2 directly (scale fused)

  hipMemsetAsync(zbeg, 0, (size_t)(zend - zbeg), stream);

  gvec_k<<<1, 64, 0, stream>>>(m1w1, m1w2, m2w1, m2w2, g);
  edge_stats_k<<<2048, 256, 0, stream>>>(ei, degS, degD, sdrr, E);
  int NB = (N + 1023) / 1024;
  scanA_k<<<2 * NB, 1024, 0, stream>>>(degS, degD, bsum, N, NB);
  scanB_k<<<1, 1, 0, stream>>>(bsum, bsumx, offS, offD, N, NB);
  scanC_k<<<2 * NB, 1024, 0, stream>>>(degS, degD, bsumx, offS, offD, N, NB);
  scatter_k<<<(E + 255) / 256, 256, 0, stream>>>(sdrr, wm, offS, offD, csw, csde, E);

  gemm1_k<<<(N + 127) / 128, 256, 0, stream>>>(x, l1w, l1b, x1q1, N);
  node_q1_k<<<(N + 3) / 4, 256, 0, stream>>>(x1q1, offS, csw, sc2, g, N);
  msg1_k<<<(N + 3) / 4, 256, 0, stream>>>(x1q1, h, offD, csde, g, N);
  gemm2_k<<<(N * 16 + 255) / 256, 256, 0, stream>>>(h, l2w, l2b, sc2, x2q2, N);
  msg2_k<<<(N + 3) / 4, 256, 0, stream>>>(x2q2, out, offD, csde, g, N);
}

// Round 6
// 1073.216 us; speedup vs baseline: 2.3914x; 1.0518x over previous
//
#include <hip/hip_runtime.h>

// CurvGN 2-layer graph net, N=100k nodes, E=3.2M edges, 256->64->16.
// Algebra: edge-MLP logits = w_mul[e] * (w>0 ? gpos[i] : gneg[i]) + b2[i];
// b2 cancels in per-src segment softmax. Segment max from per-src w endpoints.
// out[d][i] = sum_e exp(w_e*g_i) * q[src][i],  q = x*exp(-m)/(den+1e-16).
// Layer-2 scale sc2 computed in node_q1's csw scan, applied in gemm2.
// CSR build: edge_stats' degree atomicAdd returns each edge's rank within its
// segment -> scatter is ATOMIC-FREE: pos = off[node] + rank.
// R5 evidence: 6.4M atomic-with-return at ~20G/s = outstanding-latency bound
// -> unroll x4 (phase-split: loads | atomics | stores) for 8 in-flight atomics.

static __device__ __forceinline__ int ld_idx(const void* ei, long long pos, int is64) {
  return is64 ? (int)((const long long*)ei)[pos] : ((const int*)ei)[pos];
}

// ---- K1: collapse edge MLPs: g[0:64]=gpos1 g[64:128]=gneg1 g[128:144]=gpos2 g[144:160]=gneg2
__global__ void gvec_k(const float* __restrict__ w1a, const float* __restrict__ w2a,
                       const float* __restrict__ w1b, const float* __restrict__ w2b,
                       float* __restrict__ g) {
  int i = threadIdx.x;
  if (i < 64) {
    float sp = 0.f, sn = 0.f;
    for (int j = 0; j < 64; ++j) {
      float a = w1a[j], b = w2a[i * 64 + j], ab = a * b;
      sp += ab * (a > 0.f ? 1.f : 0.2f);
      sn += ab * (a < 0.f ? 1.f : 0.2f);
    }
    g[i] = sp; g[64 + i] = sn;
  }
  if (i < 16) {
    float sp = 0.f, sn = 0.f;
    for (int j = 0; j < 16; ++j) {
      float a = w1b[j], b = w2b[i * 16 + j], ab = a * b;
      sp += ab * (a > 0.f ? 1.f : 0.2f);
      sn += ab * (a < 0.f ? 1.f : 0.2f);
    }
    g[128 + i] = sp; g[144 + i] = sn;
  }
}

// ---- K2: degree histograms; atomic return values are per-edge ranks.
// Unroll x4, phase-split so 8 atomics are in flight per thread.
__global__ void edge_stats_k(const void* __restrict__ ei, int* degS, int* degD,
                             int4* __restrict__ sdrr, int E) {
  __shared__ int s64;
  if (threadIdx.x == 0) {
    const unsigned* u = (const unsigned*)ei;
    unsigned o = 0;
    int lim = (2 * E < 32) ? 2 * E : 32;
    for (int t = 1; t < lim; t += 2) o |= u[t];
    s64 = (o == 0u);   // int64 little-endian: high words of small nonneg values are 0
  }
  __syncthreads();
  int is64 = s64;
  int base = blockIdx.x * 1024 + threadIdx.x;
  int s[4], d[4], rs[4], rd[4];
  #pragma unroll
  for (int k = 0; k < 4; ++k) {
    int e = base + k * 256;
    if (e < E) { s[k] = ld_idx(ei, e, is64); d[k] = ld_idx(ei, (long long)e + E, is64); }
  }
  #pragma unroll
  for (int k = 0; k < 4; ++k) {
    int e = base + k * 256;
    if (e < E) { rs[k] = atomicAdd(&degS[s[k]], 1); rd[k] = atomicAdd(&degD[d[k]], 1); }
  }
  #pragma unroll
  for (int k = 0; k < 4; ++k) {
    int e = base + k * 256;
    if (e < E) sdrr[e] = make_int4(s[k], d[k], rs[k], rd[k]);
  }
}

// ---- scan (3 kernels); handles both deg arrays (a = blockIdx / NB)
__global__ void scanA_k(const int* __restrict__ degS, const int* __restrict__ degD,
                        int* __restrict__ bsum, int N, int NB) {
  int b = blockIdx.x, a = b / NB, bb = b % NB;
  const int* deg = a ? degD : degS;
  int i = bb * 1024 + threadIdx.x;
  int v = (i < N) ? deg[i] : 0;
  int lane = threadIdx.x & 63, wid = threadIdx.x >> 6;
  #pragma unroll
  for (int d = 32; d > 0; d >>= 1) v += __shfl_xor(v, d);
  __shared__ int ws_[16];
  if (lane == 0) ws_[wid] = v;
  __syncthreads();
  if (threadIdx.x == 0) {
    int s = 0;
    for (int t = 0; t < 16; ++t) s += ws_[t];
    bsum[a * 256 + bb] = s;
  }
}
__global__ void scanB_k(const int* __restrict__ bsum, int* __restrict__ bsumx,
                        int* offS, int* offD, int N, int NB) {
  for (int a = 0; a < 2; ++a) {
    int c = 0;
    for (int b = 0; b < NB; ++b) { bsumx[a * 256 + b] = c; c += bsum[a * 256 + b]; }
    (a ? offD : offS)[N] = c;
  }
}
__global__ void scanC_k(const int* __restrict__ degS, const int* __restrict__ degD,
                        const int* __restrict__ bsumx,
                        int* offS, int* offD, int N, int NB) {
  int b = blockIdx.x, a = b / NB, bb = b % NB;
  const int* deg = a ? degD : degS;
  int* off = a ? offD : offS;
  int i = bb * 1024 + threadIdx.x;
  int v = (i < N) ? deg[i] : 0;
  int lane = threadIdx.x & 63, wid = threadIdx.x >> 6;
  int x = v;
  #pragma unroll
  for (int d = 1; d < 64; d <<= 1) { int t = __shfl_up(x, d); if (lane >= d) x += t; }
  __shared__ int ws_[16];
  if (lane == 63) ws_[wid] = x;
  __syncthreads();
  if (wid == 0) {
    int s = (lane < 16) ? ws_[lane] : 0;
    #pragma unroll
    for (int d = 1; d < 16; d <<= 1) { int t = __shfl_up(s, d); if (lane >= d) s += t; }
    if (lane < 16) ws_[lane] = s;
  }
  __syncthreads();
  int add = (wid ? ws_[wid - 1] : 0) + bsumx[a * 256 + bb];
  if (i < N) off[i] = add + x - v;
}

// ---- K4: atomic-free scatter into CSR: pos = off[node] + rank.
// Unroll x4, phase-split: coalesced loads | off gathers | scattered stores.
__global__ void scatter_k(const int4* __restrict__ sdrr, const float* __restrict__ wm,
                          const int* __restrict__ offS, const int* __restrict__ offD,
                          float* __restrict__ csw, uint2* __restrict__ csde, int E) {
  int base = blockIdx.x * 1024 + threadIdx.x;
  int4 v[4]; float w[4]; int oS[4], oD[4];
  #pragma unroll
  for (int k = 0; k < 4; ++k) {
    int e = base + k * 256;
    if (e < E) { v[k] = sdrr[e]; w[k] = wm[e]; }
  }
  #pragma unroll
  for (int k = 0; k < 4; ++k) {
    int e = base + k * 256;
    if (e < E) { oS[k] = offS[v[k].x]; oD[k] = offD[v[k].y]; }
  }
  #pragma unroll
  for (int k = 0; k < 4; ++k) {
    int e = base + k * 256;
    if (e < E) {
      csw[oS[k] + v[k].z] = w[k];
      csde[oD[k] + v[k].w] = make_uint2((unsigned)v[k].x, __float_as_uint(w[k]));
    }
  }
}

// ---- K5: x1 = x @ lin1_w.T + b   (N x 256) x (64 x 256)^T -> N x 64
__global__ __launch_bounds__(256) void gemm1_k(const float* __restrict__ x,
                                               const float* __restrict__ W,
                                               const float* __restrict__ b,
                                               float* __restrict__ x1, int N) {
  __shared__ __align__(16) float Al[128 * 36];
  __shared__ __align__(16) float Bl[64 * 36];
  int t = threadIdx.x;
  int n0 = blockIdx.x * 128;
  int tm = t & 31, tc = t >> 5;
  int lr = t >> 3, lc = (t & 7) * 4;
  float acc[4][8];
  #pragma unroll
  for (int j = 0; j < 4; ++j)
    #pragma unroll
    for (int jj = 0; jj < 8; ++jj) acc[j][jj] = 0.f;

  for (int k0 = 0; k0 < 256; k0 += 32) {
    #pragma unroll
    for (int l = 0; l < 4; ++l) {
      int row = lr + l * 32;
      int n = n0 + row;
      float4 v = (n < N) ? *(const float4*)&x[(size_t)n * 256 + k0 + lc]
                         : make_float4(0.f, 0.f, 0.f, 0.f);
      *(float4*)&Al[row * 36 + lc] = v;
    }
    #pragma unroll
    for (int l = 0; l < 2; ++l) {
      int row = lr + l * 32;
      *(float4*)&Bl[row * 36 + lc] = *(const float4*)&W[row * 256 + k0 + lc];
    }
    __syncthreads();
    #pragma unroll
    for (int k4 = 0; k4 < 8; ++k4) {
      float4 a0 = *(const float4*)&Al[tm * 36 + k4 * 4];
      float4 a1 = *(const float4*)&Al[(tm + 32) * 36 + k4 * 4];
      float4 a2 = *(const float4*)&Al[(tm + 64) * 36 + k4 * 4];
      float4 a3 = *(const float4*)&Al[(tm + 96) * 36 + k4 * 4];
      #pragma unroll
      for (int jj = 0; jj < 8; ++jj) {
        float4 bv = *(const float4*)&Bl[(tc * 8 + jj) * 36 + k4 * 4];
        acc[0][jj] += a0.x * bv.x + a0.y * bv.y + a0.z * bv.z + a0.w * bv.w;
        acc[1][jj] += a1.x * bv.x + a1.y * bv.y + a1.z * bv.z + a1.w * bv.w;
        acc[2][jj] += a2.x * bv.x + a2.y * bv.y + a2.z * bv.z + a2.w * bv.w;
        acc[3][jj] += a3.x * bv.x + a3.y * bv.y + a3.z * bv.z + a3.w * bv.w;
      }
    }
    __syncthreads();
  }
  float bb0 = b[tc * 8 + 0], bb1 = b[tc * 8 + 1], bb2 = b[tc * 8 + 2], bb3 = b[tc * 8 + 3];
  float bb4 = b[tc * 8 + 4], bb5 = b[tc * 8 + 5], bb6 = b[tc * 8 + 6], bb7 = b[tc * 8 + 7];
  #pragma unroll
  for (int j = 0; j < 4; ++j) {
    int n = n0 + tm + j * 32;
    if (n < N) {
      float4 o0 = make_float4(acc[j][0] + bb0, acc[j][1] + bb1, acc[j][2] + bb2, acc[j][3] + bb3);
      float4 o1 = make_float4(acc[j][4] + bb4, acc[j][5] + bb5, acc[j][6] + bb6, acc[j][7] + bb7);
      *(float4*)&x1[(size_t)n * 64 + tc * 8] = o0;
      *(float4*)&x1[(size_t)n * 64 + tc * 8 + 4] = o1;
    }
  }
}

// ---- K6: q1 scale + layer-2 scale sc2, one wave per src node.
// den1: shfl-broadcast loop (64 channels x all edges).
// den2: p-strided broadcast (j=p; j+=4) -> the 4 lane-groups (p=lane>>4)
// jointly cover every chunk position; xor-{16,32} reduce at the end.
__global__ void node_q1_k(float* __restrict__ x1q1, const int* __restrict__ offS,
                          const float* __restrict__ csw, float* __restrict__ sc2,
                          const float* __restrict__ g, int N) {
  int wv = (int)(((long long)blockIdx.x * blockDim.x + threadIdx.x) >> 6);
  if (wv >= N) return;
  int lane = threadIdx.x & 63;
  int s = wv;
  int beg = offS[s], end = offS[s + 1];
  if (beg == end) return;  // empty segment: q1[s]/sc2[s] never read
  float wpmax = -3.0e38f, wpmin = 3.0e38f, wnmax = -3.0e38f, wnmin = 3.0e38f;
  int zf = 0;
  for (int t = beg + lane; t < end; t += 64) {
    float w = csw[t];
    if (w > 0.f)      { wpmax = fmaxf(wpmax, w); wpmin = fminf(wpmin, w); }
    else if (w < 0.f) { wnmax = fmaxf(wnmax, w); wnmin = fminf(wnmin, w); }
    else zf = 1;
  }
  #pragma unroll
  for (int d = 1; d < 64; d <<= 1) {
    wpmax = fmaxf(wpmax, __shfl_xor(wpmax, d));
    wpmin = fminf(wpmin, __shfl_xor(wpmin, d));
    wnmax = fmaxf(wnmax, __shfl_xor(wnmax, d));
    wnmin = fminf(wnmin, __shfl_xor(wnmin, d));
    zf |= __shfl_xor(zf, d);
  }
  int li = lane & 15, p = lane >> 4;
  float gp = g[lane], gn = g[64 + lane];
  float gp2 = g[128 + li], gn2 = g[144 + li];
  float m = -3.0e38f, m2 = -3.0e38f;
  if (wpmax > -1.0e38f) { m = fmaxf(m, gp > 0.f ? wpmax * gp : wpmin * gp);
                          m2 = fmaxf(m2, gp2 > 0.f ? wpmax * gp2 : wpmin * gp2); }
  if (wnmax > -1.0e38f) { m = fmaxf(m, gn > 0.f ? wnmax * gn : wnmin * gn);
                          m2 = fmaxf(m2, gn2 > 0.f ? wnmax * gn2 : wnmin * gn2); }
  if (zf) { m = fmaxf(m, 0.f); m2 = fmaxf(m2, 0.f); }
  float den = 0.f, den2p = 0.f;
  for (int t0 = beg; t0 < end; t0 += 64) {
    int nv = min(64, end - t0);
    float wl = (t0 + lane < end) ? csw[t0 + lane] : 0.f;
    for (int j = 0; j < nv; ++j) {
      float w = __shfl(wl, j);
      den += __expf(w * (w > 0.f ? gp : gn) - m);
    }
    for (int j = p; j < nv; j += 4) {
      float w = __shfl(wl, j);
      den2p += __expf(w * (w > 0.f ? gp2 : gn2) - m2);
    }
  }
  den2p += __shfl_xor(den2p, 16);
  den2p += __shfl_xor(den2p, 32);
  int o = s * 64 + lane;
  x1q1[o] = x1q1[o] * (__expf(-m) / (den + 1e-16f));
  if (lane < 16) sc2[s * 16 + li] = __expf(-m2) / (den2p + 1e-16f);
}

// ---- K7: h[d] = elu( sum_in exp(w*g)*q1[src] ), one wave per dst node.
// Unroll-2 + dual accumulators: keeps 2 independent gathers in flight.
__global__ void msg1_k(const float* __restrict__ q1, float* __restrict__ h,
                       const int* __restrict__ offD, const uint2* __restrict__ csde,
                       const float* __restrict__ g, int N) {
  int wv = (int)(((long long)blockIdx.x * blockDim.x + threadIdx.x) >> 6);
  if (wv >= N) return;
  int lane = threadIdx.x & 63;
  int d = wv;
  int beg = offD[d], end = offD[d + 1];
  float gp = g[lane], gn = g[64 + lane];
  float acc0 = 0.f, acc1 = 0.f;
  for (int t0 = beg; t0 < end; t0 += 64) {
    int nv = min(64, end - t0);
    uint2 ew = (t0 + lane < end) ? csde[t0 + lane] : make_uint2(0u, 0u);
    int sl = (int)ew.x;
    float wl = __uint_as_float(ew.y);
    int j = 0;
    for (; j + 1 < nv; j += 2) {
      int   sA = __shfl(sl, j);     float wA = __shfl(wl, j);
      int   sB = __shfl(sl, j + 1); float wB = __shfl(wl, j + 1);
      acc0 += __expf(wA * (wA > 0.f ? gp : gn)) * q1[sA * 64 + lane];
      acc1 += __expf(wB * (wB > 0.f ? gp : gn)) * q1[sB * 64 + lane];
    }
    if (j < nv) {
      int sA = __shfl(sl, j); float wA = __shfl(wl, j);
      acc0 += __expf(wA * (wA > 0.f ? gp : gn)) * q1[sA * 64 + lane];
    }
  }
  float acc = acc0 + acc1;
  h[d * 64 + lane] = acc > 0.f ? acc : (__expf(acc) - 1.f);
}

// ---- K5b: x2q2 = (h @ lin2_w.T + b) * sc2   (q2 directly)
__global__ void gemm2_k(const float* __restrict__ h, const float* __restrict__ W,
                        const float* __restrict__ b, const float* __restrict__ sc2,
                        float* __restrict__ x2, int N) {
  long long idx = (long long)blockIdx.x * blockDim.x + threadIdx.x;
  if (idx >= (long long)N * 16) return;
  int n = (int)(idx >> 4), i = (int)(idx & 15);
  const float* hr = h + (long long)n * 64;
  const float* wr = W + i * 64;
  float acc = 0.f;
  #pragma unroll
  for (int k = 0; k < 64; k += 4) {
    float4 a = *(const float4*)&hr[k];
    float4 w4 = *(const float4*)&wr[k];
    acc += a.x * w4.x + a.y * w4.y + a.z * w4.z + a.w * w4.w;
  }
  x2[idx] = (acc + b[i]) * sc2[idx];
}

// ---- K9: out2 aggregation + log_softmax fused
__global__ void msg2_k(const float* __restrict__ q2, float* __restrict__ out,
                       const int* __restrict__ offD, const uint2* __restrict__ csde,
                       const float* __restrict__ g, int N) {
  int wv = (int)(((long long)blockIdx.x * blockDim.x + threadIdx.x) >> 6);
  if (wv >= N) return;
  int lane = threadIdx.x & 63, i = lane & 15, p = lane >> 4;
  int d = wv;
  int beg = offD[d], end = offD[d + 1];
  float gp = g[128 + i], gn = g[144 + i];
  float accp = 0.f;
  for (int t0 = beg; t0 < end; t0 += 64) {
    int nv = min(64, end - t0);
    uint2 ew = (t0 + lane < end) ? csde[t0 + lane] : make_uint2(0u, 0u);
    int sl = (int)ew.x;
    float wl = __uint_as_float(ew.y);
    for (int j = p; j < nv; j += 4) {
      int s = __shfl(sl, j);
      float w = __shfl(wl, j);
      accp += __expf(w * (w > 0.f ? gp : gn)) * q2[s * 16 + i];
    }
  }
  float acc = accp;
  acc += __shfl_xor(acc, 16);
  acc += __shfl_xor(acc, 32);
  float mx = acc;
  #pragma unroll
  for (int d2 = 1; d2 < 16; d2 <<= 1) mx = fmaxf(mx, __shfl_xor(mx, d2));
  float se = __expf(acc - mx);
  #pragma unroll
  for (int d2 = 1; d2 < 16; d2 <<= 1) se += __shfl_xor(se, d2);
  float ls = acc - mx - __logf(se);
  if (p == 0) out[d * 16 + i] = ls;
}

extern "C" void kernel_launch(void* const* d_in, const int* in_sizes, int n_in,
                              void* d_out, int out_size, void* d_ws, size_t ws_size,
                              hipStream_t stream) {
  const float* x    = (const float*)d_in[0];
  const void*  ei   = d_in[1];
  const float* wm   = (const float*)d_in[2];
  const float* l1w  = (const float*)d_in[3];
  const float* l1b  = (const float*)d_in[4];
  const float* m1w1 = (const float*)d_in[5];
  const float* m1w2 = (const float*)d_in[6];
  const float* l2w  = (const float*)d_in[8];
  const float* l2b  = (const float*)d_in[9];
  const float* m2w1 = (const float*)d_in[10];
  const float* m2w2 = (const float*)d_in[11];
  // mlp*_b2 (d_in[7], d_in[12]) cancel in the segment softmax — unused.

  int N = in_sizes[0] / 256;
  int E = in_sizes[2];
  float* out = (float*)d_out;

  char* base = (char*)d_ws;
  size_t off = 0;
  auto alloc = [&](size_t bytes) -> char* {
    char* p = base + off;
    off = (off + bytes + 255) & ~(size_t)255;
    return p;
  };
  char* zbeg = base + off;
  int* degS = (int*)alloc((size_t)N * 4);
  int* degD = (int*)alloc((size_t)N * 4);
  char* zend = base + off;
  int* offS  = (int*)alloc((size_t)(N + 1) * 4);
  int* offD  = (int*)alloc((size_t)(N + 1) * 4);
  float* sc2 = (float*)alloc((size_t)N * 16 * 4);
  float* g   = (float*)alloc(1024);
  int* bsum  = (int*)alloc(2 * 256 * 4);
  int* bsumx = (int*)alloc(2 * 256 * 4);
  int4*  sdrr = (int4*)alloc((size_t)E * 16);
  float* csw  = (float*)alloc((size_t)E * 4);
  uint2* csde = (uint2*)alloc((size_t)E * 8);
  float* x1q1 = (float*)alloc((size_t)N * 64 * 4);   // x1, then q1 in-place
  float* h    = (float*)alloc((size_t)N * 64 * 4);
  float* x2q2 = (float*)alloc((size_t)N * 16 * 4);   // q2 directly (scale fused)

  hipMemsetAsync(zbeg, 0, (size_t)(zend - zbeg), stream);

  gvec_k<<<1, 64, 0, stream>>>(m1w1, m1w2, m2w1, m2w2, g);
  edge_stats_k<<<(E + 1023) / 1024, 256, 0, stream>>>(ei, degS, degD, sdrr, E);
  int NB = (N + 1023) / 1024;
  scanA_k<<<2 * NB, 1024, 0, stream>>>(degS, degD, bsum, N, NB);
  scanB_k<<<1, 1, 0, stream>>>(bsum, bsumx, offS, offD, N, NB);
  scanC_k<<<2 * NB, 1024, 0, stream>>>(degS, degD, bsumx, offS, offD, N, NB);
  scatter_k<<<(E + 1023) / 1024, 256, 0, stream>>>(sdrr, wm, offS, offD, csw, csde, E);

  gemm1_k<<<(N + 127) / 128, 256, 0, stream>>>(x, l1w, l1b, x1q1, N);
  node_q1_k<<<(N + 3) / 4, 256, 0, stream>>>(x1q1, offS, csw, sc2, g, N);
  msg1_k<<<(N + 3) / 4, 256, 0, stream>>>(x1q1, h, offD, csde, g, N);
  gemm2_k<<<(N * 16 + 255) / 256, 256, 0, stream>>>(h, l2w, l2b, sc2, x2q2, N);
  msg2_k<<<(N + 3) / 4, 256, 0, stream>>>(x2q2, out, offD, csde, g, N);
}

// Round 7
// 918.587 us; speedup vs baseline: 2.7940x; 1.1683x over previous
//
#include <hip/hip_runtime.h>

// CurvGN 2-layer graph net, N=100k nodes, E=3.2M edges, 256->64->16.
// Algebra: edge-MLP logits = w_mul[e] * (w>0 ? gpos[i] : gneg[i]) + b2[i];
// b2 cancels in per-src segment softmax. Segment max from per-src w endpoints.
// out[d][i] = sum_e exp(w_e*g_i) * q[src][i],  q = x*exp(-m)/(den+1e-16).
// Layer-2 scale sc2 computed in node_q1's csw scan, applied in gemm2.
// CSR build: edge_stats' degree atomicAdd returns each edge's rank within its
// segment -> scatter is ATOMIC-FREE: pos = off[node] + rank.
// R3/R5/R6 evidence: scattered device atomics cap at ~21G/s regardless of
// locality/outstanding count -> hide gemm1 (graph-independent) INSIDE the
// atomic kernel: fused grid, every 5th block runs a gemm1 tile. sdrr packs
// (s, d, rs|rd<<16, w_bits) so scatter reads one int4 stream only.

static __device__ __forceinline__ int ld_idx(const void* ei, long long pos, int is64) {
  return is64 ? (int)((const long long*)ei)[pos] : ((const int*)ei)[pos];
}

// ---- K1: collapse edge MLPs: g[0:64]=gpos1 g[64:128]=gneg1 g[128:144]=gpos2 g[144:160]=gneg2
__global__ void gvec_k(const float* __restrict__ w1a, const float* __restrict__ w2a,
                       const float* __restrict__ w1b, const float* __restrict__ w2b,
                       float* __restrict__ g) {
  int i = threadIdx.x;
  if (i < 64) {
    float sp = 0.f, sn = 0.f;
    for (int j = 0; j < 64; ++j) {
      float a = w1a[j], b = w2a[i * 64 + j], ab = a * b;
      sp += ab * (a > 0.f ? 1.f : 0.2f);
      sn += ab * (a < 0.f ? 1.f : 0.2f);
    }
    g[i] = sp; g[64 + i] = sn;
  }
  if (i < 16) {
    float sp = 0.f, sn = 0.f;
    for (int j = 0; j < 16; ++j) {
      float a = w1b[j], b = w2b[i * 16 + j], ab = a * b;
      sp += ab * (a > 0.f ? 1.f : 0.2f);
      sn += ab * (a < 0.f ? 1.f : 0.2f);
    }
    g[128 + i] = sp; g[144 + i] = sn;
  }
}

// ---- K2 (fused): block role by blockIdx: r==4 -> gemm1 tile, else edge_stats.
// Edge path: degree histograms; atomic returns are per-edge ranks; packs
// (s, d, rs|rd<<16, w_bits) as one coalesced int4.
// Gemm path: x1 = x @ lin1_w.T + b, 128 rows x 64 cols per block.
__global__ __launch_bounds__(256) void fused_es_gemm1_k(
    const void* __restrict__ ei, const float* __restrict__ wm,
    int* degS, int* degD, int4* __restrict__ sdrr, int E, int EB,
    const float* __restrict__ x, const float* __restrict__ W,
    const float* __restrict__ b, float* __restrict__ x1, int N, int GB) {
  __shared__ __align__(16) float Al[128 * 36];
  __shared__ __align__(16) float Bl[64 * 36];
  int k = blockIdx.x, q = k / 5, r = k - q * 5;
  if (r == 4) {
    // ---------------- gemm1 tile ----------------
    int gid = q;
    if (gid >= GB) return;
    int t = threadIdx.x;
    int n0 = gid * 128;
    int tm = t & 31, tc = t >> 5;
    int lr = t >> 3, lc = (t & 7) * 4;
    float acc[4][8];
    #pragma unroll
    for (int j = 0; j < 4; ++j)
      #pragma unroll
      for (int jj = 0; jj < 8; ++jj) acc[j][jj] = 0.f;
    for (int k0 = 0; k0 < 256; k0 += 32) {
      #pragma unroll
      for (int l = 0; l < 4; ++l) {
        int row = lr + l * 32;
        int n = n0 + row;
        float4 v = (n < N) ? *(const float4*)&x[(size_t)n * 256 + k0 + lc]
                           : make_float4(0.f, 0.f, 0.f, 0.f);
        *(float4*)&Al[row * 36 + lc] = v;
      }
      #pragma unroll
      for (int l = 0; l < 2; ++l) {
        int row = lr + l * 32;
        *(float4*)&Bl[row * 36 + lc] = *(const float4*)&W[row * 256 + k0 + lc];
      }
      __syncthreads();
      #pragma unroll
      for (int k4 = 0; k4 < 8; ++k4) {
        float4 a0 = *(const float4*)&Al[tm * 36 + k4 * 4];
        float4 a1 = *(const float4*)&Al[(tm + 32) * 36 + k4 * 4];
        float4 a2 = *(const float4*)&Al[(tm + 64) * 36 + k4 * 4];
        float4 a3 = *(const float4*)&Al[(tm + 96) * 36 + k4 * 4];
        #pragma unroll
        for (int jj = 0; jj < 8; ++jj) {
          float4 bv = *(const float4*)&Bl[(tc * 8 + jj) * 36 + k4 * 4];
          acc[0][jj] += a0.x * bv.x + a0.y * bv.y + a0.z * bv.z + a0.w * bv.w;
          acc[1][jj] += a1.x * bv.x + a1.y * bv.y + a1.z * bv.z + a1.w * bv.w;
          acc[2][jj] += a2.x * bv.x + a2.y * bv.y + a2.z * bv.z + a2.w * bv.w;
          acc[3][jj] += a3.x * bv.x + a3.y * bv.y + a3.z * bv.z + a3.w * bv.w;
        }
      }
      __syncthreads();
    }
    float bb[8];
    #pragma unroll
    for (int jj = 0; jj < 8; ++jj) bb[jj] = b[tc * 8 + jj];
    #pragma unroll
    for (int j = 0; j < 4; ++j) {
      int n = n0 + tm + j * 32;
      if (n < N) {
        float4 o0 = make_float4(acc[j][0] + bb[0], acc[j][1] + bb[1], acc[j][2] + bb[2], acc[j][3] + bb[3]);
        float4 o1 = make_float4(acc[j][4] + bb[4], acc[j][5] + bb[5], acc[j][6] + bb[6], acc[j][7] + bb[7]);
        *(float4*)&x1[(size_t)n * 64 + tc * 8] = o0;
        *(float4*)&x1[(size_t)n * 64 + tc * 8 + 4] = o1;
      }
    }
  } else {
    // ---------------- edge_stats (unroll x4, phase-split) ----------------
    int eid = k - q;           // bijective over blocks with r<4
    if (eid >= EB) return;
    __shared__ int s64;
    if (threadIdx.x == 0) {
      const unsigned* u = (const unsigned*)ei;
      unsigned o = 0;
      int lim = (2 * E < 32) ? 2 * E : 32;
      for (int t = 1; t < lim; t += 2) o |= u[t];
      s64 = (o == 0u);   // int64 little-endian: high words of small nonneg values are 0
    }
    __syncthreads();
    int is64 = s64;
    int base = eid * 1024 + threadIdx.x;
    int s[4], d[4], rs[4], rd[4]; float w[4];
    #pragma unroll
    for (int kk = 0; kk < 4; ++kk) {
      int e = base + kk * 256;
      if (e < E) {
        s[kk] = ld_idx(ei, e, is64);
        d[kk] = ld_idx(ei, (long long)e + E, is64);
        w[kk] = wm[e];
      }
    }
    #pragma unroll
    for (int kk = 0; kk < 4; ++kk) {
      int e = base + kk * 256;
      if (e < E) { rs[kk] = atomicAdd(&degS[s[kk]], 1); rd[kk] = atomicAdd(&degD[d[kk]], 1); }
    }
    #pragma unroll
    for (int kk = 0; kk < 4; ++kk) {
      int e = base + kk * 256;
      if (e < E)
        sdrr[e] = make_int4(s[kk], d[kk], rs[kk] | (rd[kk] << 16), (int)__float_as_uint(w[kk]));
    }
  }
}

// ---- scan (3 kernels); handles both deg arrays (a = blockIdx / NB)
__global__ void scanA_k(const int* __restrict__ degS, const int* __restrict__ degD,
                        int* __restrict__ bsum, int N, int NB) {
  int b = blockIdx.x, a = b / NB, bb = b % NB;
  const int* deg = a ? degD : degS;
  int i = bb * 1024 + threadIdx.x;
  int v = (i < N) ? deg[i] : 0;
  int lane = threadIdx.x & 63, wid = threadIdx.x >> 6;
  #pragma unroll
  for (int d = 32; d > 0; d >>= 1) v += __shfl_xor(v, d);
  __shared__ int ws_[16];
  if (lane == 0) ws_[wid] = v;
  __syncthreads();
  if (threadIdx.x == 0) {
    int s = 0;
    for (int t = 0; t < 16; ++t) s += ws_[t];
    bsum[a * 256 + bb] = s;
  }
}
__global__ void scanB_k(const int* __restrict__ bsum, int* __restrict__ bsumx,
                        int* offS, int* offD, int N, int NB) {
  for (int a = 0; a < 2; ++a) {
    int c = 0;
    for (int b = 0; b < NB; ++b) { bsumx[a * 256 + b] = c; c += bsum[a * 256 + b]; }
    (a ? offD : offS)[N] = c;
  }
}
__global__ void scanC_k(const int* __restrict__ degS, const int* __restrict__ degD,
                        const int* __restrict__ bsumx,
                        int* offS, int* offD, int N, int NB) {
  int b = blockIdx.x, a = b / NB, bb = b % NB;
  const int* deg = a ? degD : degS;
  int* off = a ? offD : offS;
  int i = bb * 1024 + threadIdx.x;
  int v = (i < N) ? deg[i] : 0;
  int lane = threadIdx.x & 63, wid = threadIdx.x >> 6;
  int x = v;
  #pragma unroll
  for (int d = 1; d < 64; d <<= 1) { int t = __shfl_up(x, d); if (lane >= d) x += t; }
  __shared__ int ws_[16];
  if (lane == 63) ws_[wid] = x;
  __syncthreads();
  if (wid == 0) {
    int s = (lane < 16) ? ws_[lane] : 0;
    #pragma unroll
    for (int d = 1; d < 16; d <<= 1) { int t = __shfl_up(s, d); if (lane >= d) s += t; }
    if (lane < 16) ws_[lane] = s;
  }
  __syncthreads();
  int add = (wid ? ws_[wid - 1] : 0) + bsumx[a * 256 + bb];
  if (i < N) off[i] = add + x - v;
}

// ---- K4: atomic-free scatter into CSR: pos = off[node] + rank.
// Single int4 stream; unroll x4, phase-split: loads | off gathers | stores.
__global__ void scatter_k(const int4* __restrict__ sdrr,
                          const int* __restrict__ offS, const int* __restrict__ offD,
                          float* __restrict__ csw, uint2* __restrict__ csde, int E) {
  int base = blockIdx.x * 1024 + threadIdx.x;
  int4 v[4]; int oS[4], oD[4];
  #pragma unroll
  for (int k = 0; k < 4; ++k) {
    int e = base + k * 256;
    if (e < E) v[k] = sdrr[e];
  }
  #pragma unroll
  for (int k = 0; k < 4; ++k) {
    int e = base + k * 256;
    if (e < E) { oS[k] = offS[v[k].x]; oD[k] = offD[v[k].y]; }
  }
  #pragma unroll
  for (int k = 0; k < 4; ++k) {
    int e = base + k * 256;
    if (e < E) {
      unsigned z = (unsigned)v[k].z;
      csw[oS[k] + (int)(z & 0xffffu)] = __uint_as_float((unsigned)v[k].w);
      csde[oD[k] + (int)(z >> 16)] = make_uint2((unsigned)v[k].x, (unsigned)v[k].w);
    }
  }
}

// ---- K6: q1 scale + layer-2 scale sc2, one wave per src node.
// den1: shfl-broadcast loop (64 channels x all edges).
// den2: p-strided broadcast (j=p; j+=4) -> the 4 lane-groups (p=lane>>4)
// jointly cover every chunk position; xor-{16,32} reduce at the end.
__global__ void node_q1_k(float* __restrict__ x1q1, const int* __restrict__ offS,
                          const float* __restrict__ csw, float* __restrict__ sc2,
                          const float* __restrict__ g, int N) {
  int wv = (int)(((long long)blockIdx.x * blockDim.x + threadIdx.x) >> 6);
  if (wv >= N) return;
  int lane = threadIdx.x & 63;
  int s = wv;
  int beg = offS[s], end = offS[s + 1];
  if (beg == end) return;  // empty segment: q1[s]/sc2[s] never read
  float wpmax = -3.0e38f, wpmin = 3.0e38f, wnmax = -3.0e38f, wnmin = 3.0e38f;
  int zf = 0;
  for (int t = beg + lane; t < end; t += 64) {
    float w = csw[t];
    if (w > 0.f)      { wpmax = fmaxf(wpmax, w); wpmin = fminf(wpmin, w); }
    else if (w < 0.f) { wnmax = fmaxf(wnmax, w); wnmin = fminf(wnmin, w); }
    else zf = 1;
  }
  #pragma unroll
  for (int d = 1; d < 64; d <<= 1) {
    wpmax = fmaxf(wpmax, __shfl_xor(wpmax, d));
    wpmin = fminf(wpmin, __shfl_xor(wpmin, d));
    wnmax = fmaxf(wnmax, __shfl_xor(wnmax, d));
    wnmin = fminf(wnmin, __shfl_xor(wnmin, d));
    zf |= __shfl_xor(zf, d);
  }
  int li = lane & 15, p = lane >> 4;
  float gp = g[lane], gn = g[64 + lane];
  float gp2 = g[128 + li], gn2 = g[144 + li];
  float m = -3.0e38f, m2 = -3.0e38f;
  if (wpmax > -1.0e38f) { m = fmaxf(m, gp > 0.f ? wpmax * gp : wpmin * gp);
                          m2 = fmaxf(m2, gp2 > 0.f ? wpmax * gp2 : wpmin * gp2); }
  if (wnmax > -1.0e38f) { m = fmaxf(m, gn > 0.f ? wnmax * gn : wnmin * gn);
                          m2 = fmaxf(m2, gn2 > 0.f ? wnmax * gn2 : wnmin * gn2); }
  if (zf) { m = fmaxf(m, 0.f); m2 = fmaxf(m2, 0.f); }
  float den = 0.f, den2p = 0.f;
  for (int t0 = beg; t0 < end; t0 += 64) {
    int nv = min(64, end - t0);
    float wl = (t0 + lane < end) ? csw[t0 + lane] : 0.f;
    for (int j = 0; j < nv; ++j) {
      float w = __shfl(wl, j);
      den += __expf(w * (w > 0.f ? gp : gn) - m);
    }
    for (int j = p; j < nv; j += 4) {
      float w = __shfl(wl, j);
      den2p += __expf(w * (w > 0.f ? gp2 : gn2) - m2);
    }
  }
  den2p += __shfl_xor(den2p, 16);
  den2p += __shfl_xor(den2p, 32);
  int o = s * 64 + lane;
  x1q1[o] = x1q1[o] * (__expf(-m) / (den + 1e-16f));
  if (lane < 16) sc2[s * 16 + li] = __expf(-m2) / (den2p + 1e-16f);
}

// ---- K7: h[d] = elu( sum_in exp(w*g)*q1[src] ), one wave per dst node.
// Unroll-2 + dual accumulators: keeps 2 independent gathers in flight.
__global__ void msg1_k(const float* __restrict__ q1, float* __restrict__ h,
                       const int* __restrict__ offD, const uint2* __restrict__ csde,
                       const float* __restrict__ g, int N) {
  int wv = (int)(((long long)blockIdx.x * blockDim.x + threadIdx.x) >> 6);
  if (wv >= N) return;
  int lane = threadIdx.x & 63;
  int d = wv;
  int beg = offD[d], end = offD[d + 1];
  float gp = g[lane], gn = g[64 + lane];
  float acc0 = 0.f, acc1 = 0.f;
  for (int t0 = beg; t0 < end; t0 += 64) {
    int nv = min(64, end - t0);
    uint2 ew = (t0 + lane < end) ? csde[t0 + lane] : make_uint2(0u, 0u);
    int sl = (int)ew.x;
    float wl = __uint_as_float(ew.y);
    int j = 0;
    for (; j + 1 < nv; j += 2) {
      int   sA = __shfl(sl, j);     float wA = __shfl(wl, j);
      int   sB = __shfl(sl, j + 1); float wB = __shfl(wl, j + 1);
      acc0 += __expf(wA * (wA > 0.f ? gp : gn)) * q1[sA * 64 + lane];
      acc1 += __expf(wB * (wB > 0.f ? gp : gn)) * q1[sB * 64 + lane];
    }
    if (j < nv) {
      int sA = __shfl(sl, j); float wA = __shfl(wl, j);
      acc0 += __expf(wA * (wA > 0.f ? gp : gn)) * q1[sA * 64 + lane];
    }
  }
  float acc = acc0 + acc1;
  h[d * 64 + lane] = acc > 0.f ? acc : (__expf(acc) - 1.f);
}

// ---- K5b: x2q2 = (h @ lin2_w.T + b) * sc2   (q2 directly)
__global__ void gemm2_k(const float* __restrict__ h, const float* __restrict__ W,
                        const float* __restrict__ b, const float* __restrict__ sc2,
                        float* __restrict__ x2, int N) {
  long long idx = (long long)blockIdx.x * blockDim.x + threadIdx.x;
  if (idx >= (long long)N * 16) return;
  int n = (int)(idx >> 4), i = (int)(idx & 15);
  const float* hr = h + (long long)n * 64;
  const float* wr = W + i * 64;
  float acc = 0.f;
  #pragma unroll
  for (int k = 0; k < 64; k += 4) {
    float4 a = *(const float4*)&hr[k];
    float4 w4 = *(const float4*)&wr[k];
    acc += a.x * w4.x + a.y * w4.y + a.z * w4.z + a.w * w4.w;
  }
  x2[idx] = (acc + b[i]) * sc2[idx];
}

// ---- K9: out2 aggregation + log_softmax fused
__global__ void msg2_k(const float* __restrict__ q2, float* __restrict__ out,
                       const int* __restrict__ offD, const uint2* __restrict__ csde,
                       const float* __restrict__ g, int N) {
  int wv = (int)(((long long)blockIdx.x * blockDim.x + threadIdx.x) >> 6);
  if (wv >= N) return;
  int lane = threadIdx.x & 63, i = lane & 15, p = lane >> 4;
  int d = wv;
  int beg = offD[d], end = offD[d + 1];
  float gp = g[128 + i], gn = g[144 + i];
  float accp = 0.f;
  for (int t0 = beg; t0 < end; t0 += 64) {
    int nv = min(64, end - t0);
    uint2 ew = (t0 + lane < end) ? csde[t0 + lane] : make_uint2(0u, 0u);
    int sl = (int)ew.x;
    float wl = __uint_as_float(ew.y);
    for (int j = p; j < nv; j += 4) {
      int s = __shfl(sl, j);
      float w = __shfl(wl, j);
      accp += __expf(w * (w > 0.f ? gp : gn)) * q2[s * 16 + i];
    }
  }
  float acc = accp;
  acc += __shfl_xor(acc, 16);
  acc += __shfl_xor(acc, 32);
  float mx = acc;
  #pragma unroll
  for (int d2 = 1; d2 < 16; d2 <<= 1) mx = fmaxf(mx, __shfl_xor(mx, d2));
  float se = __expf(acc - mx);
  #pragma unroll
  for (int d2 = 1; d2 < 16; d2 <<= 1) se += __shfl_xor(se, d2);
  float ls = acc - mx - __logf(se);
  if (p == 0) out[d * 16 + i] = ls;
}

extern "C" void kernel_launch(void* const* d_in, const int* in_sizes, int n_in,
                              void* d_out, int out_size, void* d_ws, size_t ws_size,
                              hipStream_t stream) {
  const float* x    = (const float*)d_in[0];
  const void*  ei   = d_in[1];
  const float* wm   = (const float*)d_in[2];
  const float* l1w  = (const float*)d_in[3];
  const float* l1b  = (const float*)d_in[4];
  const float* m1w1 = (const float*)d_in[5];
  const float* m1w2 = (const float*)d_in[6];
  const float* l2w  = (const float*)d_in[8];
  const float* l2b  = (const float*)d_in[9];
  const float* m2w1 = (const float*)d_in[10];
  const float* m2w2 = (const float*)d_in[11];
  // mlp*_b2 (d_in[7], d_in[12]) cancel in the segment softmax — unused.

  int N = in_sizes[0] / 256;
  int E = in_sizes[2];
  float* out = (float*)d_out;

  char* base = (char*)d_ws;
  size_t off = 0;
  auto alloc = [&](size_t bytes) -> char* {
    char* p = base + off;
    off = (off + bytes + 255) & ~(size_t)255;
    return p;
  };
  char* zbeg = base + off;
  int* degS = (int*)alloc((size_t)N * 4);
  int* degD = (int*)alloc((size_t)N * 4);
  char* zend = base + off;
  int* offS  = (int*)alloc((size_t)(N + 1) * 4);
  int* offD  = (int*)alloc((size_t)(N + 1) * 4);
  float* sc2 = (float*)alloc((size_t)N * 16 * 4);
  float* g   = (float*)alloc(1024);
  int* bsum  = (int*)alloc(2 * 256 * 4);
  int* bsumx = (int*)alloc(2 * 256 * 4);
  int4*  sdrr = (int4*)alloc((size_t)E * 16);
  float* csw  = (float*)alloc((size_t)E * 4);
  uint2* csde = (uint2*)alloc((size_t)E * 8);
  float* x1q1 = (float*)alloc((size_t)N * 64 * 4);   // x1, then q1 in-place
  float* h    = (float*)alloc((size_t)N * 64 * 4);
  float* x2q2 = (float*)alloc((size_t)N * 16 * 4);   // q2 directly (scale fused)

  hipMemsetAsync(zbeg, 0, (size_t)(zend - zbeg), stream);

  gvec_k<<<1, 64, 0, stream>>>(m1w1, m1w2, m2w1, m2w2, g);

  int EB = (E + 1023) / 1024;           // edge blocks
  int GB = (N + 127) / 128;             // gemm1 tiles
  // grid: blocks with k%5==4 are gemm tiles (k/5 < GB), others map to
  // eid = k - k/5 (bijective). grid = 5*GB covers gid in [0,GB); need
  // enough r<4 blocks for EB: k - k/5 >= EB  ->  grid >= EB + (EB+3)/4.
  int grid = 5 * GB;
  int need = EB + (EB + 3) / 4;
  if (grid < need) grid = need;
  fused_es_gemm1_k<<<grid, 256, 0, stream>>>(ei, wm, degS, degD, sdrr, E, EB,
                                             x, l1w, l1b, x1q1, N, GB);

  int NB = (N + 1023) / 1024;
  scanA_k<<<2 * NB, 1024, 0, stream>>>(degS, degD, bsum, N, NB);
  scanB_k<<<1, 1, 0, stream>>>(bsum, bsumx, offS, offD, N, NB);
  scanC_k<<<2 * NB, 1024, 0, stream>>>(degS, degD, bsumx, offS, offD, N, NB);
  scatter_k<<<(E + 1023) / 1024, 256, 0, stream>>>(sdrr, offS, offD, csw, csde, E);

  node_q1_k<<<(N + 3) / 4, 256, 0, stream>>>(x1q1, offS, csw, sc2, g, N);
  msg1_k<<<(N + 3) / 4, 256, 0, stream>>>(x1q1, h, offD, csde, g, N);
  gemm2_k<<<(N * 16 + 255) / 256, 256, 0, stream>>>(h, l2w, l2b, sc2, x2q2, N);
  msg2_k<<<(N + 3) / 4, 256, 0, stream>>>(x2q2, out, offD, csde, g, N);
}